// Round 1
// baseline (1347.823 us; speedup 1.0000x reference)
//
#include <hip/hip_runtime.h>
#include <hip/hip_bf16.h>
#include <math.h>

#define N_NODES 50000
#define N_EDGES 800000
#define N_GRAPHS 64
#define NUM_CLASSES 10
#define SCAN_BLOCKS ((N_NODES + 255) / 256)   // 196

// ---------------- init ----------------
__global__ void k_init(float* deg, float* pooled, float* gcount) {
    int i = blockIdx.x * blockDim.x + threadIdx.x;
    if (i < N_NODES) deg[i] = 1.0f;                 // self loop
    if (i < N_GRAPHS * 256) pooled[i] = 0.0f;
    if (i < N_GRAPHS) gcount[i] = 0.0f;
}

// ---------------- degree ----------------
__global__ void k_deg(const int* __restrict__ dst, float* deg) {
    int e = blockIdx.x * blockDim.x + threadIdx.x;
    if (e < N_EDGES) atomicAdd(&deg[dst[e]], 1.0f);
}

__global__ void k_dinv(float* deg, int* cnt) {
    int i = blockIdx.x * blockDim.x + threadIdx.x;
    if (i < N_NODES) {
        float d = deg[i];
        deg[i] = rsqrtf(d);          // deg buffer becomes dinv
        cnt[i] = (int)d - 1;         // incoming non-self edges
    }
}

// ---------------- CSR build: two-level exclusive scan ----------------
__global__ void k_scan1(const int* __restrict__ cnt, int* row_ptr, int* blockSums) {
    __shared__ int s[256];
    int t = threadIdx.x;
    int i = blockIdx.x * 256 + t;
    int v = (i < N_NODES) ? cnt[i] : 0;
    s[t] = v; __syncthreads();
    for (int off = 1; off < 256; off <<= 1) {
        int x = (t >= off) ? s[t - off] : 0;
        __syncthreads();
        s[t] += x;
        __syncthreads();
    }
    if (i < N_NODES) row_ptr[i] = s[t] - v;          // exclusive within block
    if (t == 255) blockSums[blockIdx.x] = s[255];
}

__global__ void k_scan2(int* blockSums) {
    __shared__ int s[256];
    int t = threadIdx.x;
    int v = (t < SCAN_BLOCKS) ? blockSums[t] : 0;
    s[t] = v; __syncthreads();
    for (int off = 1; off < 256; off <<= 1) {
        int x = (t >= off) ? s[t - off] : 0;
        __syncthreads();
        s[t] += x;
        __syncthreads();
    }
    if (t < SCAN_BLOCKS) blockSums[t] = s[t] - v;    // exclusive
}

__global__ void k_scan3(int* row_ptr, const int* __restrict__ blockSums, int* cursor) {
    int i = blockIdx.x * blockDim.x + threadIdx.x;
    if (i < N_NODES) {
        int rp = row_ptr[i] + blockSums[i >> 8];
        row_ptr[i] = rp;
        cursor[i] = rp;
    }
    if (i == 0) row_ptr[N_NODES] = N_EDGES;
}

__global__ void k_scatter(const int* __restrict__ src, const int* __restrict__ dst,
                          const float* __restrict__ dinv, int* cursor,
                          int* csr_src, float* csr_norm) {
    int e = blockIdx.x * blockDim.x + threadIdx.x;
    if (e < N_EDGES) {
        int s = src[e], d = dst[e];
        int pos = atomicAdd(&cursor[d], 1);
        csr_src[pos] = s;
        csr_norm[pos] = dinv[s] * dinv[d];
    }
}

// ---------------- dense transform: Hout = Hin @ W ----------------
template<int DIN, int DOUT>
__global__ void k_matmul(const float* __restrict__ Hin, const float* __restrict__ W,
                         float* __restrict__ Hout) {
    constexpr int G = 256 / DOUT;        // column-groups per block
    constexpr int ROWS = 16;             // rows per group
    constexpr int RPB = G * ROWS;        // rows per block
    __shared__ float lds[RPB * DIN];
    int t = threadIdx.x;
    int row0 = blockIdx.x * RPB;
    const int base = row0 * DIN;
    const int lim = N_NODES * DIN - base;
    for (int idx = t; idx < RPB * DIN; idx += 256)
        lds[idx] = (idx < lim) ? Hin[base + idx] : 0.0f;
    __syncthreads();
    int j = t % DOUT;
    int g = t / DOUT;
    float acc[ROWS];
    #pragma unroll
    for (int r = 0; r < ROWS; r++) acc[r] = 0.0f;
    for (int k = 0; k < DIN; k++) {
        float w = W[k * DOUT + j];
        #pragma unroll
        for (int r = 0; r < ROWS; r++)
            acc[r] += lds[(g * ROWS + r) * DIN + k] * w;
    }
    #pragma unroll
    for (int r = 0; r < ROWS; r++) {
        int gr = row0 + g * ROWS + r;
        if (gr < N_NODES) Hout[gr * DOUT + j] = acc[r];
    }
}

// ---------------- aggregate + bias + relu ----------------
template<int DOUT>
__global__ void k_aggregate(const float* __restrict__ tmp, const int* __restrict__ row_ptr,
                            const int* __restrict__ csr_src, const float* __restrict__ csr_norm,
                            const float* __restrict__ dinv, const float* __restrict__ bias,
                            float* __restrict__ Hout) {
    constexpr int G = 256 / DOUT;
    int t = threadIdx.x;
    int f = t % DOUT;
    int g = t / DOUT;
    int node = blockIdx.x * G + g;
    if (node >= N_NODES) return;
    float di = dinv[node];
    float acc = di * di * tmp[node * DOUT + f];      // self loop
    int e0 = row_ptr[node], e1 = row_ptr[node + 1];
    for (int e = e0; e < e1; e++) {
        int s = csr_src[e];
        float nrm = csr_norm[e];
        acc += nrm * tmp[s * DOUT + f];
    }
    float v = acc + bias[f];
    Hout[node * DOUT + f] = v > 0.0f ? v : 0.0f;
}

// ---------------- pooling ----------------
__global__ void k_counts(const int* __restrict__ batch, float* gcount) {
    int i = blockIdx.x * blockDim.x + threadIdx.x;
    if (i < N_NODES) atomicAdd(&gcount[batch[i]], 1.0f);
}

#define POOL_CHUNK 256
__global__ void k_pool(const float* __restrict__ h, const int* __restrict__ batch,
                       float* pooled) {
    int t = threadIdx.x;                 // feature 0..255
    int n0 = blockIdx.x * POOL_CHUNK;
    int n1 = n0 + POOL_CHUNK; if (n1 > N_NODES) n1 = N_NODES;
    float acc = 0.0f;
    int cur = batch[n0];
    for (int i = n0; i < n1; i++) {
        int g = batch[i];
        if (g != cur) {
            atomicAdd(&pooled[cur * 256 + t], acc);
            acc = 0.0f; cur = g;
        }
        acc += h[i * 256 + t];
    }
    atomicAdd(&pooled[cur * 256 + t], acc);
}

// ---------------- FC + log_softmax (one wave per graph) ----------------
__global__ void k_final(const float* __restrict__ pooled, const float* __restrict__ gcount,
                        const float* __restrict__ fcW, const float* __restrict__ fcb,
                        float* __restrict__ out) {
    int g = blockIdx.x;
    int t = threadIdx.x;                 // 0..63
    float p[4];
    #pragma unroll
    for (int m = 0; m < 4; m++) p[m] = pooled[g * 256 + t + 64 * m];
    float inv = 1.0f / fmaxf(gcount[g], 1.0f);
    float logits[NUM_CLASSES];
    #pragma unroll
    for (int j = 0; j < NUM_CLASSES; j++) {
        float s = 0.0f;
        #pragma unroll
        for (int m = 0; m < 4; m++) s += p[m] * fcW[(t + 64 * m) * NUM_CLASSES + j];
        for (int off = 32; off > 0; off >>= 1) s += __shfl_xor(s, off);
        logits[j] = s * inv + fcb[j];
    }
    float mx = logits[0];
    #pragma unroll
    for (int j = 1; j < NUM_CLASSES; j++) mx = fmaxf(mx, logits[j]);
    float se = 0.0f;
    #pragma unroll
    for (int j = 0; j < NUM_CLASSES; j++) se += expf(logits[j] - mx);
    float lse = mx + logf(se);
    if (t < NUM_CLASSES) out[g * NUM_CLASSES + t] = logits[t] - lse;
}

extern "C" void kernel_launch(void* const* d_in, const int* in_sizes, int n_in,
                              void* d_out, int out_size, void* d_ws, size_t ws_size,
                              hipStream_t stream) {
    const float* x     = (const float*)d_in[0];
    const int*   ei    = (const int*)d_in[1];
    const int*   src   = ei;
    const int*   dst   = ei + N_EDGES;
    const int*   batch = (const int*)d_in[2];
    const float* W1 = (const float*)d_in[3];  const float* b1 = (const float*)d_in[4];
    const float* W2 = (const float*)d_in[5];  const float* b2 = (const float*)d_in[6];
    const float* W3 = (const float*)d_in[7];  const float* b3 = (const float*)d_in[8];
    const float* W4 = (const float*)d_in[9];  const float* b4 = (const float*)d_in[10];
    const float* fcW = (const float*)d_in[11]; const float* fcb = (const float*)d_in[12];
    float* out = (float*)d_out;

    char* ws = (char*)d_ws;
    float* bufA     = (float*)ws; ws += (size_t)N_NODES * 256 * 4;   // tmp (matmul out)
    float* bufB     = (float*)ws; ws += (size_t)N_NODES * 256 * 4;   // h
    float* dinv     = (float*)ws; ws += (size_t)N_NODES * 4;         // deg -> dinv
    int*   cnt      = (int*)ws;   ws += (size_t)N_NODES * 4;
    int*   row_ptr  = (int*)ws;   ws += (size_t)(N_NODES + 4) * 4;
    int*   cursor   = (int*)ws;   ws += (size_t)N_NODES * 4;
    int*   blockSums= (int*)ws;   ws += 256 * 4;
    int*   csr_src  = (int*)ws;   ws += (size_t)N_EDGES * 4;
    float* csr_norm = (float*)ws; ws += (size_t)N_EDGES * 4;
    float* pooled   = (float*)ws; ws += (size_t)N_GRAPHS * 256 * 4;
    float* gcount   = (float*)ws; ws += (size_t)N_GRAPHS * 4;

    const int TB = 256;
    // normalization + CSR
    k_init<<<(N_NODES + TB - 1) / TB, TB, 0, stream>>>(dinv, pooled, gcount);
    k_deg<<<(N_EDGES + TB - 1) / TB, TB, 0, stream>>>(dst, dinv);
    k_dinv<<<SCAN_BLOCKS, TB, 0, stream>>>(dinv, cnt);
    k_scan1<<<SCAN_BLOCKS, TB, 0, stream>>>(cnt, row_ptr, blockSums);
    k_scan2<<<1, TB, 0, stream>>>(blockSums);
    k_scan3<<<SCAN_BLOCKS, TB, 0, stream>>>(row_ptr, blockSums, cursor);
    k_scatter<<<(N_EDGES + TB - 1) / TB, TB, 0, stream>>>(src, dst, dinv, cursor, csr_src, csr_norm);

    // layer 1: 5 -> 32
    k_matmul<5, 32><<<(N_NODES + 127) / 128, TB, 0, stream>>>(x, W1, bufA);
    k_aggregate<32><<<(N_NODES + 7) / 8, TB, 0, stream>>>(bufA, row_ptr, csr_src, csr_norm, dinv, b1, bufB);
    // layer 2: 32 -> 64
    k_matmul<32, 64><<<(N_NODES + 63) / 64, TB, 0, stream>>>(bufB, W2, bufA);
    k_aggregate<64><<<(N_NODES + 3) / 4, TB, 0, stream>>>(bufA, row_ptr, csr_src, csr_norm, dinv, b2, bufB);
    // layer 3: 64 -> 128
    k_matmul<64, 128><<<(N_NODES + 31) / 32, TB, 0, stream>>>(bufB, W3, bufA);
    k_aggregate<128><<<(N_NODES + 1) / 2, TB, 0, stream>>>(bufA, row_ptr, csr_src, csr_norm, dinv, b3, bufB);
    // layer 4: 128 -> 256
    k_matmul<128, 256><<<(N_NODES + 15) / 16, TB, 0, stream>>>(bufB, W4, bufA);
    k_aggregate<256><<<N_NODES, TB, 0, stream>>>(bufA, row_ptr, csr_src, csr_norm, dinv, b4, bufB);

    // pooling + classifier
    k_counts<<<SCAN_BLOCKS, TB, 0, stream>>>(batch, gcount);
    k_pool<<<(N_NODES + POOL_CHUNK - 1) / POOL_CHUNK, TB, 0, stream>>>(bufB, batch, pooled);
    k_final<<<N_GRAPHS, 64, 0, stream>>>(pooled, gcount, fcW, fcb, out);
}

// Round 2
// 627.506 us; speedup vs baseline: 2.1479x; 2.1479x over previous
//
#include <hip/hip_runtime.h>
#include <hip/hip_bf16.h>
#include <math.h>

#define N_NODES 50000
#define N_EDGES 800000
#define N_GRAPHS 64
#define NUM_CLASSES 10
#define SCAN_BLOCKS ((N_NODES + 255) / 256)   // 196

// ---------------- init ----------------
__global__ void k_init(float* deg, float* pooled) {
    int i = blockIdx.x * blockDim.x + threadIdx.x;
    if (i < N_NODES) deg[i] = 1.0f;                 // self loop
    if (i < N_GRAPHS * 256) pooled[i] = 0.0f;
}

// ---------------- degree ----------------
__global__ void k_deg(const int* __restrict__ dst, float* deg) {
    int e = blockIdx.x * blockDim.x + threadIdx.x;
    if (e < N_EDGES) atomicAdd(&deg[dst[e]], 1.0f);
}

__global__ void k_dinv(float* deg, int* cnt) {
    int i = blockIdx.x * blockDim.x + threadIdx.x;
    if (i < N_NODES) {
        float d = deg[i];
        deg[i] = rsqrtf(d);          // deg buffer becomes dinv
        cnt[i] = (int)d - 1;         // incoming non-self edges
    }
}

// ---------------- CSR build: two-level exclusive scan ----------------
__global__ void k_scan1(const int* __restrict__ cnt, int* row_ptr, int* blockSums) {
    __shared__ int s[256];
    int t = threadIdx.x;
    int i = blockIdx.x * 256 + t;
    int v = (i < N_NODES) ? cnt[i] : 0;
    s[t] = v; __syncthreads();
    for (int off = 1; off < 256; off <<= 1) {
        int x = (t >= off) ? s[t - off] : 0;
        __syncthreads();
        s[t] += x;
        __syncthreads();
    }
    if (i < N_NODES) row_ptr[i] = s[t] - v;          // exclusive within block
    if (t == 255) blockSums[blockIdx.x] = s[255];
}

__global__ void k_scan2(int* blockSums) {
    __shared__ int s[256];
    int t = threadIdx.x;
    int v = (t < SCAN_BLOCKS) ? blockSums[t] : 0;
    s[t] = v; __syncthreads();
    for (int off = 1; off < 256; off <<= 1) {
        int x = (t >= off) ? s[t - off] : 0;
        __syncthreads();
        s[t] += x;
        __syncthreads();
    }
    if (t < SCAN_BLOCKS) blockSums[t] = s[t] - v;    // exclusive
}

__global__ void k_scan3(int* row_ptr, const int* __restrict__ blockSums, int* cursor) {
    int i = blockIdx.x * blockDim.x + threadIdx.x;
    if (i < N_NODES) {
        int rp = row_ptr[i] + blockSums[i >> 8];
        row_ptr[i] = rp;
        cursor[i] = rp;
    }
    if (i == 0) row_ptr[N_NODES] = N_EDGES;
}

__global__ void k_scatter(const int* __restrict__ src, const int* __restrict__ dst,
                          const float* __restrict__ dinv, int* cursor,
                          int* csr_src, float* csr_norm) {
    int e = blockIdx.x * blockDim.x + threadIdx.x;
    if (e < N_EDGES) {
        int s = src[e], d = dst[e];
        int pos = atomicAdd(&cursor[d], 1);
        csr_src[pos] = s;
        csr_norm[pos] = dinv[s] * dinv[d];
    }
}

// ---------------- aggregate (pre-transform): out = D^-1/2 (A+I) D^-1/2 h ----------------
// D = 5 special case: 8 threads/node, lanes f>=5 idle
__global__ void k_agg5(const float* __restrict__ h, const int* __restrict__ row_ptr,
                       const int* __restrict__ csr_src, const float* __restrict__ csr_norm,
                       const float* __restrict__ dinv, float* __restrict__ out) {
    int t = threadIdx.x;
    int f = t & 7;
    int g = t >> 3;
    int node = blockIdx.x * 32 + g;
    if (node >= N_NODES || f >= 5) return;
    float di = dinv[node];
    float acc = di * di * h[node * 5 + f];
    int e0 = row_ptr[node], e1 = row_ptr[node + 1];
    for (int e = e0; e < e1; e++)
        acc += csr_norm[e] * h[csr_src[e] * 5 + f];
    out[node * 5 + f] = acc;
}

// D multiple of 4: float4 per thread
template<int D>
__global__ void k_agg(const float* __restrict__ h, const int* __restrict__ row_ptr,
                      const int* __restrict__ csr_src, const float* __restrict__ csr_norm,
                      const float* __restrict__ dinv, float* __restrict__ out) {
    constexpr int DV = D / 4;
    constexpr int G = 256 / DV;
    const float4* h4 = (const float4*)h;
    float4* out4 = (float4*)out;
    int t = threadIdx.x;
    int f = t % DV;
    int g = t / DV;
    int node = blockIdx.x * G + g;
    if (node >= N_NODES) return;
    float di = dinv[node];
    float4 v = h4[node * DV + f];
    float s2 = di * di;
    float4 acc;
    acc.x = s2 * v.x; acc.y = s2 * v.y; acc.z = s2 * v.z; acc.w = s2 * v.w;
    int e0 = row_ptr[node], e1 = row_ptr[node + 1];
    for (int e = e0; e < e1; e++) {
        int s = csr_src[e];
        float nrm = csr_norm[e];
        float4 u = h4[s * DV + f];
        acc.x += nrm * u.x; acc.y += nrm * u.y; acc.z += nrm * u.z; acc.w += nrm * u.w;
    }
    out4[node * DV + f] = acc;
}

// ---------------- dense transform + bias + relu: Hout = relu(Hin @ W + b) ----------------
template<int DIN, int DOUT>
__global__ void k_matmul(const float* __restrict__ Hin, const float* __restrict__ W,
                         const float* __restrict__ bias, float* __restrict__ Hout) {
    constexpr int G = 256 / DOUT;        // column-groups per block
    constexpr int ROWS = 16;             // rows per group
    constexpr int RPB = G * ROWS;        // rows per block
    __shared__ float lds[RPB * DIN];
    int t = threadIdx.x;
    int row0 = blockIdx.x * RPB;
    const int base = row0 * DIN;
    const int lim = N_NODES * DIN - base;
    for (int idx = t; idx < RPB * DIN; idx += 256)
        lds[idx] = (idx < lim) ? Hin[base + idx] : 0.0f;
    __syncthreads();
    int j = t % DOUT;
    int g = t / DOUT;
    float b = bias[j];
    float acc[ROWS];
    #pragma unroll
    for (int r = 0; r < ROWS; r++) acc[r] = 0.0f;
    for (int k = 0; k < DIN; k++) {
        float w = W[k * DOUT + j];
        #pragma unroll
        for (int r = 0; r < ROWS; r++)
            acc[r] += lds[(g * ROWS + r) * DIN + k] * w;
    }
    #pragma unroll
    for (int r = 0; r < ROWS; r++) {
        int gr = row0 + g * ROWS + r;
        if (gr < N_NODES) {
            float v = acc[r] + b;
            Hout[gr * DOUT + j] = v > 0.0f ? v : 0.0f;
        }
    }
}

// ---------------- graph counts via binary search (batch is sorted) ----------------
__global__ void k_counts_bs(const int* __restrict__ batch, float* gcount) {
    int g = threadIdx.x;
    if (g >= N_GRAPHS) return;
    int lo = 0, hi = N_NODES;
    while (lo < hi) { int m = (lo + hi) >> 1; if (batch[m] < g) lo = m + 1; else hi = m; }
    int start = lo;
    lo = 0; hi = N_NODES;
    while (lo < hi) { int m = (lo + hi) >> 1; if (batch[m] < g + 1) lo = m + 1; else hi = m; }
    gcount[g] = (float)(lo - start);
}

// ---------------- pooling ----------------
#define POOL_CHUNK 64
__global__ void k_pool(const float* __restrict__ h, const int* __restrict__ batch,
                       float* pooled) {
    int t = threadIdx.x;                 // feature 0..255
    int n0 = blockIdx.x * POOL_CHUNK;
    int n1 = n0 + POOL_CHUNK; if (n1 > N_NODES) n1 = N_NODES;
    float acc = 0.0f;
    int cur = batch[n0];
    for (int i = n0; i < n1; i++) {
        int g = batch[i];
        if (g != cur) {
            atomicAdd(&pooled[cur * 256 + t], acc);
            acc = 0.0f; cur = g;
        }
        acc += h[i * 256 + t];
    }
    atomicAdd(&pooled[cur * 256 + t], acc);
}

// ---------------- FC + log_softmax (one wave per graph) ----------------
__global__ void k_final(const float* __restrict__ pooled, const float* __restrict__ gcount,
                        const float* __restrict__ fcW, const float* __restrict__ fcb,
                        float* __restrict__ out) {
    int g = blockIdx.x;
    int t = threadIdx.x;                 // 0..63
    float p[4];
    #pragma unroll
    for (int m = 0; m < 4; m++) p[m] = pooled[g * 256 + t + 64 * m];
    float inv = 1.0f / fmaxf(gcount[g], 1.0f);
    float logits[NUM_CLASSES];
    #pragma unroll
    for (int j = 0; j < NUM_CLASSES; j++) {
        float s = 0.0f;
        #pragma unroll
        for (int m = 0; m < 4; m++) s += p[m] * fcW[(t + 64 * m) * NUM_CLASSES + j];
        for (int off = 32; off > 0; off >>= 1) s += __shfl_xor(s, off);
        logits[j] = s * inv + fcb[j];
    }
    float mx = logits[0];
    #pragma unroll
    for (int j = 1; j < NUM_CLASSES; j++) mx = fmaxf(mx, logits[j]);
    float se = 0.0f;
    #pragma unroll
    for (int j = 0; j < NUM_CLASSES; j++) se += expf(logits[j] - mx);
    float lse = mx + logf(se);
    if (t < NUM_CLASSES) out[g * NUM_CLASSES + t] = logits[t] - lse;
}

extern "C" void kernel_launch(void* const* d_in, const int* in_sizes, int n_in,
                              void* d_out, int out_size, void* d_ws, size_t ws_size,
                              hipStream_t stream) {
    const float* x     = (const float*)d_in[0];
    const int*   ei    = (const int*)d_in[1];
    const int*   src   = ei;
    const int*   dst   = ei + N_EDGES;
    const int*   batch = (const int*)d_in[2];
    const float* W1 = (const float*)d_in[3];  const float* b1 = (const float*)d_in[4];
    const float* W2 = (const float*)d_in[5];  const float* b2 = (const float*)d_in[6];
    const float* W3 = (const float*)d_in[7];  const float* b3 = (const float*)d_in[8];
    const float* W4 = (const float*)d_in[9];  const float* b4 = (const float*)d_in[10];
    const float* fcW = (const float*)d_in[11]; const float* fcb = (const float*)d_in[12];
    float* out = (float*)d_out;

    char* ws = (char*)d_ws;
    float* bufA     = (float*)ws; ws += (size_t)N_NODES * 256 * 4;   // agg buffer
    float* bufB     = (float*)ws; ws += (size_t)N_NODES * 256 * 4;   // h buffer
    float* dinv     = (float*)ws; ws += (size_t)N_NODES * 4;         // deg -> dinv
    int*   cnt      = (int*)ws;   ws += (size_t)N_NODES * 4;
    int*   row_ptr  = (int*)ws;   ws += (size_t)(N_NODES + 4) * 4;
    int*   cursor   = (int*)ws;   ws += (size_t)N_NODES * 4;
    int*   blockSums= (int*)ws;   ws += 256 * 4;
    int*   csr_src  = (int*)ws;   ws += (size_t)N_EDGES * 4;
    float* csr_norm = (float*)ws; ws += (size_t)N_EDGES * 4;
    float* pooled   = (float*)ws; ws += (size_t)N_GRAPHS * 256 * 4;
    float* gcount   = (float*)ws; ws += (size_t)N_GRAPHS * 4;

    const int TB = 256;
    // normalization + CSR
    k_init<<<(N_NODES + TB - 1) / TB, TB, 0, stream>>>(dinv, pooled);
    k_deg<<<(N_EDGES + TB - 1) / TB, TB, 0, stream>>>(dst, dinv);
    k_dinv<<<SCAN_BLOCKS, TB, 0, stream>>>(dinv, cnt);
    k_scan1<<<SCAN_BLOCKS, TB, 0, stream>>>(cnt, row_ptr, blockSums);
    k_scan2<<<1, TB, 0, stream>>>(blockSums);
    k_scan3<<<SCAN_BLOCKS, TB, 0, stream>>>(row_ptr, blockSums, cursor);
    k_scatter<<<(N_EDGES + TB - 1) / TB, TB, 0, stream>>>(src, dst, dinv, cursor, csr_src, csr_norm);
    k_counts_bs<<<1, 64, 0, stream>>>(batch, gcount);

    // layer 1: agg(x)[5] -> mm 5->32
    k_agg5<<<(N_NODES + 31) / 32, TB, 0, stream>>>(x, row_ptr, csr_src, csr_norm, dinv, bufA);
    k_matmul<5, 32><<<(N_NODES + 127) / 128, TB, 0, stream>>>(bufA, W1, b1, bufB);
    // layer 2: agg[32] -> mm 32->64
    k_agg<32><<<(N_NODES + 31) / 32, TB, 0, stream>>>(bufB, row_ptr, csr_src, csr_norm, dinv, bufA);
    k_matmul<32, 64><<<(N_NODES + 63) / 64, TB, 0, stream>>>(bufA, W2, b2, bufB);
    // layer 3: agg[64] -> mm 64->128
    k_agg<64><<<(N_NODES + 15) / 16, TB, 0, stream>>>(bufB, row_ptr, csr_src, csr_norm, dinv, bufA);
    k_matmul<64, 128><<<(N_NODES + 31) / 32, TB, 0, stream>>>(bufA, W3, b3, bufB);
    // layer 4: agg[128] -> mm 128->256
    k_agg<128><<<(N_NODES + 7) / 8, TB, 0, stream>>>(bufB, row_ptr, csr_src, csr_norm, dinv, bufA);
    k_matmul<128, 256><<<(N_NODES + 15) / 16, TB, 0, stream>>>(bufA, W4, b4, bufB);

    // pooling + classifier
    k_pool<<<(N_NODES + POOL_CHUNK - 1) / POOL_CHUNK, TB, 0, stream>>>(bufB, batch, pooled);
    k_final<<<N_GRAPHS, 64, 0, stream>>>(pooled, gcount, fcW, fcb, out);
}

// Round 3
// 454.343 us; speedup vs baseline: 2.9665x; 1.3811x over previous
//
#include <hip/hip_runtime.h>
#include <hip/hip_bf16.h>
#include <math.h>

#define N_NODES 50000
#define N_EDGES 800000
#define N_GRAPHS 64
#define NUM_CLASSES 10
#define SCAN_BLOCKS ((N_NODES + 255) / 256)   // 196

// ---------------- init ----------------
__global__ void k_init(float* deg, float* pooled) {
    int i = blockIdx.x * blockDim.x + threadIdx.x;
    if (i < N_NODES) deg[i] = 1.0f;                 // self loop
    if (i < N_GRAPHS * 256) pooled[i] = 0.0f;
}

// ---------------- degree ----------------
__global__ void k_deg(const int* __restrict__ dst, float* deg) {
    int e = blockIdx.x * blockDim.x + threadIdx.x;
    if (e < N_EDGES) atomicAdd(&deg[dst[e]], 1.0f);
}

__global__ void k_dinv(float* deg, int* cnt) {
    int i = blockIdx.x * blockDim.x + threadIdx.x;
    if (i < N_NODES) {
        float d = deg[i];
        deg[i] = rsqrtf(d);          // deg buffer becomes dinv
        cnt[i] = (int)d - 1;         // incoming non-self edges
    }
}

// ---------------- CSR build: two-level exclusive scan ----------------
__global__ void k_scan1(const int* __restrict__ cnt, int* row_ptr, int* blockSums) {
    __shared__ int s[256];
    int t = threadIdx.x;
    int i = blockIdx.x * 256 + t;
    int v = (i < N_NODES) ? cnt[i] : 0;
    s[t] = v; __syncthreads();
    for (int off = 1; off < 256; off <<= 1) {
        int x = (t >= off) ? s[t - off] : 0;
        __syncthreads();
        s[t] += x;
        __syncthreads();
    }
    if (i < N_NODES) row_ptr[i] = s[t] - v;          // exclusive within block
    if (t == 255) blockSums[blockIdx.x] = s[255];
}

__global__ void k_scan2(int* blockSums) {
    __shared__ int s[256];
    int t = threadIdx.x;
    int v = (t < SCAN_BLOCKS) ? blockSums[t] : 0;
    s[t] = v; __syncthreads();
    for (int off = 1; off < 256; off <<= 1) {
        int x = (t >= off) ? s[t - off] : 0;
        __syncthreads();
        s[t] += x;
        __syncthreads();
    }
    if (t < SCAN_BLOCKS) blockSums[t] = s[t] - v;    // exclusive
}

__global__ void k_scan3(int* row_ptr, const int* __restrict__ blockSums, int* cursor) {
    int i = blockIdx.x * blockDim.x + threadIdx.x;
    if (i < N_NODES) {
        int rp = row_ptr[i] + blockSums[i >> 8];
        row_ptr[i] = rp;
        cursor[i] = rp;
    }
    if (i == 0) row_ptr[N_NODES] = N_EDGES;
}

__global__ void k_scatter(const int* __restrict__ src, const int* __restrict__ dst,
                          const float* __restrict__ dinv, int* cursor,
                          int* csr_src, float* csr_norm) {
    int e = blockIdx.x * blockDim.x + threadIdx.x;
    if (e < N_EDGES) {
        int s = src[e], d = dst[e];
        int pos = atomicAdd(&cursor[d], 1);
        csr_src[pos] = s;
        csr_norm[pos] = dinv[s] * dinv[d];
    }
}

// ---------------- aggregate (pre-transform): out = D^-1/2 (A+I) D^-1/2 h ----------------
// D = 5 special case: 8 threads/node, lanes f>=5 idle
__global__ void k_agg5(const float* __restrict__ h, const int* __restrict__ row_ptr,
                       const int* __restrict__ csr_src, const float* __restrict__ csr_norm,
                       const float* __restrict__ dinv, float* __restrict__ out) {
    int t = threadIdx.x;
    int f = t & 7;
    int g = t >> 3;
    int node = blockIdx.x * 32 + g;
    if (node >= N_NODES || f >= 5) return;
    float di = dinv[node];
    float acc = di * di * h[node * 5 + f];
    int e0 = row_ptr[node], e1 = row_ptr[node + 1];
    for (int e = e0; e < e1; e++)
        acc += csr_norm[e] * h[csr_src[e] * 5 + f];
    out[node * 5 + f] = acc;
}

// D multiple of 4: float4 per thread
template<int D>
__global__ void k_agg(const float* __restrict__ h, const int* __restrict__ row_ptr,
                      const int* __restrict__ csr_src, const float* __restrict__ csr_norm,
                      const float* __restrict__ dinv, float* __restrict__ out) {
    constexpr int DV = D / 4;
    constexpr int G = 256 / DV;
    const float4* h4 = (const float4*)h;
    float4* out4 = (float4*)out;
    int t = threadIdx.x;
    int f = t % DV;
    int g = t / DV;
    int node = blockIdx.x * G + g;
    if (node >= N_NODES) return;
    float di = dinv[node];
    float4 v = h4[node * DV + f];
    float s2 = di * di;
    float4 acc;
    acc.x = s2 * v.x; acc.y = s2 * v.y; acc.z = s2 * v.z; acc.w = s2 * v.w;
    int e0 = row_ptr[node], e1 = row_ptr[node + 1];
    for (int e = e0; e < e1; e++) {
        int s = csr_src[e];
        float nrm = csr_norm[e];
        float4 u = h4[s * DV + f];
        acc.x += nrm * u.x; acc.y += nrm * u.y; acc.z += nrm * u.z; acc.w += nrm * u.w;
    }
    out4[node * DV + f] = acc;
}

// ---------------- layer-1 matmul (K=5): relu(Hin @ W + b) ----------------
template<int DIN, int DOUT>
__global__ void k_matmul(const float* __restrict__ Hin, const float* __restrict__ W,
                         const float* __restrict__ bias, float* __restrict__ Hout) {
    constexpr int G = 256 / DOUT;        // column-groups per block
    constexpr int ROWS = 16;             // rows per group
    constexpr int RPB = G * ROWS;        // rows per block
    __shared__ float lds[RPB * DIN];
    int t = threadIdx.x;
    int row0 = blockIdx.x * RPB;
    const int base = row0 * DIN;
    const int lim = N_NODES * DIN - base;
    for (int idx = t; idx < RPB * DIN; idx += 256)
        lds[idx] = (idx < lim) ? Hin[base + idx] : 0.0f;
    __syncthreads();
    int j = t % DOUT;
    int g = t / DOUT;
    float b = bias[j];
    float acc[ROWS];
    #pragma unroll
    for (int r = 0; r < ROWS; r++) acc[r] = 0.0f;
    for (int k = 0; k < DIN; k++) {
        float w = W[k * DOUT + j];
        #pragma unroll
        for (int r = 0; r < ROWS; r++)
            acc[r] += lds[(g * ROWS + r) * DIN + k] * w;
    }
    #pragma unroll
    for (int r = 0; r < ROWS; r++) {
        int gr = row0 + g * ROWS + r;
        if (gr < N_NODES) {
            float v = acc[r] + b;
            Hout[gr * DOUT + j] = v > 0.0f ? v : 0.0f;
        }
    }
}

// ---------------- register-blocked GEMM: relu(A @ W + b) ----------------
// BM=128, BN=64, BK=32, 256 threads, 8x4 thread tile.
// grid.x = DOUT/BN (col blocks, fast-varying -> same A tile adjacent in dispatch)
// grid.y = ceil(N/BM)
template<int DIN, int DOUT>
__global__ __launch_bounds__(256) void k_gemm(const float* __restrict__ A,
                                              const float* __restrict__ W,
                                              const float* __restrict__ bias,
                                              float* __restrict__ C) {
    constexpr int BM = 128, BN = 64, BK = 32;
    __shared__ float As[BK][BM + 4];   // transposed A tile, padded (132 floats: 16B-aligned rows)
    __shared__ float Ws[BK][BN + 4];   // W tile, padded (68 floats)
    int t  = threadIdx.x;
    int tx = t & 15;          // 0..15 -> col group (4 cols)
    int ty = t >> 4;          // 0..15 -> row group (8 rows)
    int row0 = blockIdx.y * BM;
    int n0   = blockIdx.x * BN;

    float acc[8][4];
    #pragma unroll
    for (int i = 0; i < 8; i++)
        #pragma unroll
        for (int j = 0; j < 4; j++) acc[i][j] = 0.0f;

    for (int k0 = 0; k0 < DIN; k0 += BK) {
        // stage A slab (BM x BK), transposed into As[k][row]
        #pragma unroll
        for (int q = 0; q < 4; q++) {
            int r  = q * 32 + (t >> 3);   // 0..127
            int c4 = t & 7;               // 0..7 (float4 within 32 cols)
            int gr = row0 + r;
            float4 v = make_float4(0.f, 0.f, 0.f, 0.f);
            if (gr < N_NODES) v = *(const float4*)&A[(size_t)gr * DIN + k0 + c4 * 4];
            As[c4 * 4 + 0][r] = v.x;
            As[c4 * 4 + 1][r] = v.y;
            As[c4 * 4 + 2][r] = v.z;
            As[c4 * 4 + 3][r] = v.w;
        }
        // stage W slab (BK x BN)
        #pragma unroll
        for (int p = 0; p < 2; p++) {     // 32*64 floats / (256 thr * 4) = 2
            int idx = t + 256 * p;
            int k   = idx >> 4;           // 0..31
            int c4  = idx & 15;           // 0..15
            float4 v = *(const float4*)&W[(size_t)(k0 + k) * DOUT + n0 + c4 * 4];
            *(float4*)&Ws[k][c4 * 4] = v;
        }
        __syncthreads();
        #pragma unroll
        for (int k = 0; k < BK; k++) {
            float4 a0 = *(const float4*)&As[k][ty * 8];
            float4 a1 = *(const float4*)&As[k][ty * 8 + 4];
            float4 w  = *(const float4*)&Ws[k][tx * 4];
            float ar[8] = {a0.x, a0.y, a0.z, a0.w, a1.x, a1.y, a1.z, a1.w};
            float wr[4] = {w.x, w.y, w.z, w.w};
            #pragma unroll
            for (int i = 0; i < 8; i++)
                #pragma unroll
                for (int j = 0; j < 4; j++)
                    acc[i][j] += ar[i] * wr[j];
        }
        __syncthreads();
    }

    float4 b = *(const float4*)&bias[n0 + tx * 4];
    float br[4] = {b.x, b.y, b.z, b.w};
    #pragma unroll
    for (int i = 0; i < 8; i++) {
        int gr = row0 + ty * 8 + i;
        if (gr < N_NODES) {
            float4 o;
            o.x = fmaxf(acc[i][0] + br[0], 0.f);
            o.y = fmaxf(acc[i][1] + br[1], 0.f);
            o.z = fmaxf(acc[i][2] + br[2], 0.f);
            o.w = fmaxf(acc[i][3] + br[3], 0.f);
            *(float4*)&C[(size_t)gr * DOUT + n0 + tx * 4] = o;
        }
    }
}

// ---------------- graph counts via binary search (batch is sorted) ----------------
__global__ void k_counts_bs(const int* __restrict__ batch, float* gcount) {
    int g = threadIdx.x;
    if (g >= N_GRAPHS) return;
    int lo = 0, hi = N_NODES;
    while (lo < hi) { int m = (lo + hi) >> 1; if (batch[m] < g) lo = m + 1; else hi = m; }
    int start = lo;
    lo = 0; hi = N_NODES;
    while (lo < hi) { int m = (lo + hi) >> 1; if (batch[m] < g + 1) lo = m + 1; else hi = m; }
    gcount[g] = (float)(lo - start);
}

// ---------------- pooling ----------------
#define POOL_CHUNK 64
__global__ void k_pool(const float* __restrict__ h, const int* __restrict__ batch,
                       float* pooled) {
    int t = threadIdx.x;                 // feature 0..255
    int n0 = blockIdx.x * POOL_CHUNK;
    int n1 = n0 + POOL_CHUNK; if (n1 > N_NODES) n1 = N_NODES;
    float acc = 0.0f;
    int cur = batch[n0];
    for (int i = n0; i < n1; i++) {
        int g = batch[i];
        if (g != cur) {
            atomicAdd(&pooled[cur * 256 + t], acc);
            acc = 0.0f; cur = g;
        }
        acc += h[i * 256 + t];
    }
    atomicAdd(&pooled[cur * 256 + t], acc);
}

// ---------------- FC + log_softmax (one wave per graph) ----------------
__global__ void k_final(const float* __restrict__ pooled, const float* __restrict__ gcount,
                        const float* __restrict__ fcW, const float* __restrict__ fcb,
                        float* __restrict__ out) {
    int g = blockIdx.x;
    int t = threadIdx.x;                 // 0..63
    float p[4];
    #pragma unroll
    for (int m = 0; m < 4; m++) p[m] = pooled[g * 256 + t + 64 * m];
    float inv = 1.0f / fmaxf(gcount[g], 1.0f);
    float logits[NUM_CLASSES];
    #pragma unroll
    for (int j = 0; j < NUM_CLASSES; j++) {
        float s = 0.0f;
        #pragma unroll
        for (int m = 0; m < 4; m++) s += p[m] * fcW[(t + 64 * m) * NUM_CLASSES + j];
        for (int off = 32; off > 0; off >>= 1) s += __shfl_xor(s, off);
        logits[j] = s * inv + fcb[j];
    }
    float mx = logits[0];
    #pragma unroll
    for (int j = 1; j < NUM_CLASSES; j++) mx = fmaxf(mx, logits[j]);
    float se = 0.0f;
    #pragma unroll
    for (int j = 0; j < NUM_CLASSES; j++) se += expf(logits[j] - mx);
    float lse = mx + logf(se);
    if (t < NUM_CLASSES) out[g * NUM_CLASSES + t] = logits[t] - lse;
}

extern "C" void kernel_launch(void* const* d_in, const int* in_sizes, int n_in,
                              void* d_out, int out_size, void* d_ws, size_t ws_size,
                              hipStream_t stream) {
    const float* x     = (const float*)d_in[0];
    const int*   ei    = (const int*)d_in[1];
    const int*   src   = ei;
    const int*   dst   = ei + N_EDGES;
    const int*   batch = (const int*)d_in[2];
    const float* W1 = (const float*)d_in[3];  const float* b1 = (const float*)d_in[4];
    const float* W2 = (const float*)d_in[5];  const float* b2 = (const float*)d_in[6];
    const float* W3 = (const float*)d_in[7];  const float* b3 = (const float*)d_in[8];
    const float* W4 = (const float*)d_in[9];  const float* b4 = (const float*)d_in[10];
    const float* fcW = (const float*)d_in[11]; const float* fcb = (const float*)d_in[12];
    float* out = (float*)d_out;

    char* ws = (char*)d_ws;
    float* bufA     = (float*)ws; ws += (size_t)N_NODES * 256 * 4;   // agg buffer
    float* bufB     = (float*)ws; ws += (size_t)N_NODES * 256 * 4;   // h buffer
    float* dinv     = (float*)ws; ws += (size_t)N_NODES * 4;         // deg -> dinv
    int*   cnt      = (int*)ws;   ws += (size_t)N_NODES * 4;
    int*   row_ptr  = (int*)ws;   ws += (size_t)(N_NODES + 4) * 4;
    int*   cursor   = (int*)ws;   ws += (size_t)N_NODES * 4;
    int*   blockSums= (int*)ws;   ws += 256 * 4;
    int*   csr_src  = (int*)ws;   ws += (size_t)N_EDGES * 4;
    float* csr_norm = (float*)ws; ws += (size_t)N_EDGES * 4;
    float* pooled   = (float*)ws; ws += (size_t)N_GRAPHS * 256 * 4;
    float* gcount   = (float*)ws; ws += (size_t)N_GRAPHS * 4;

    const int TB = 256;
    // normalization + CSR
    k_init<<<(N_NODES + TB - 1) / TB, TB, 0, stream>>>(dinv, pooled);
    k_deg<<<(N_EDGES + TB - 1) / TB, TB, 0, stream>>>(dst, dinv);
    k_dinv<<<SCAN_BLOCKS, TB, 0, stream>>>(dinv, cnt);
    k_scan1<<<SCAN_BLOCKS, TB, 0, stream>>>(cnt, row_ptr, blockSums);
    k_scan2<<<1, TB, 0, stream>>>(blockSums);
    k_scan3<<<SCAN_BLOCKS, TB, 0, stream>>>(row_ptr, blockSums, cursor);
    k_scatter<<<(N_EDGES + TB - 1) / TB, TB, 0, stream>>>(src, dst, dinv, cursor, csr_src, csr_norm);
    k_counts_bs<<<1, 64, 0, stream>>>(batch, gcount);

    const int NBM = (N_NODES + 127) / 128;   // 391
    // layer 1: agg(x)[5] -> mm 5->32
    k_agg5<<<(N_NODES + 31) / 32, TB, 0, stream>>>(x, row_ptr, csr_src, csr_norm, dinv, bufA);
    k_matmul<5, 32><<<(N_NODES + 127) / 128, TB, 0, stream>>>(bufA, W1, b1, bufB);
    // layer 2: agg[32] -> gemm 32->64
    k_agg<32><<<(N_NODES + 31) / 32, TB, 0, stream>>>(bufB, row_ptr, csr_src, csr_norm, dinv, bufA);
    k_gemm<32, 64><<<dim3(1, NBM), TB, 0, stream>>>(bufA, W2, b2, bufB);
    // layer 3: agg[64] -> gemm 64->128
    k_agg<64><<<(N_NODES + 15) / 16, TB, 0, stream>>>(bufB, row_ptr, csr_src, csr_norm, dinv, bufA);
    k_gemm<64, 128><<<dim3(2, NBM), TB, 0, stream>>>(bufA, W3, b3, bufB);
    // layer 4: agg[128] -> gemm 128->256
    k_agg<128><<<(N_NODES + 7) / 8, TB, 0, stream>>>(bufB, row_ptr, csr_src, csr_norm, dinv, bufA);
    k_gemm<128, 256><<<dim3(4, NBM), TB, 0, stream>>>(bufA, W4, b4, bufB);

    // pooling + classifier
    k_pool<<<(N_NODES + POOL_CHUNK - 1) / POOL_CHUNK, TB, 0, stream>>>(bufB, batch, pooled);
    k_final<<<N_GRAPHS, 64, 0, stream>>>(pooled, gcount, fcW, fcb, out);
}

// Round 4
// 396.036 us; speedup vs baseline: 3.4033x; 1.1472x over previous
//
#include <hip/hip_runtime.h>
#include <hip/hip_bf16.h>
#include <math.h>

#define N_NODES 50000
#define N_EDGES 800000
#define N_GRAPHS 64
#define NUM_CLASSES 10
#define SCAN_BLOCKS ((N_NODES + 255) / 256)   // 196

// fp32 -> bf16 round-to-nearest-even (values are finite post-relu)
__device__ inline unsigned short f2bf(float f) {
    unsigned int u = __float_as_uint(f);
    u += 0x7fffu + ((u >> 16) & 1u);
    return (unsigned short)(u >> 16);
}
__device__ inline void bf8_unpack(uint4 v, float* o) {
    o[0] = __uint_as_float(v.x << 16); o[1] = __uint_as_float(v.x & 0xffff0000u);
    o[2] = __uint_as_float(v.y << 16); o[3] = __uint_as_float(v.y & 0xffff0000u);
    o[4] = __uint_as_float(v.z << 16); o[5] = __uint_as_float(v.z & 0xffff0000u);
    o[6] = __uint_as_float(v.w << 16); o[7] = __uint_as_float(v.w & 0xffff0000u);
}

// ---------------- init ----------------
__global__ void k_init(float* deg, float* pooled) {
    int i = blockIdx.x * blockDim.x + threadIdx.x;
    if (i < N_NODES) deg[i] = 1.0f;                 // self loop
    if (i < N_GRAPHS * 256) pooled[i] = 0.0f;
}

// ---------------- degree ----------------
__global__ void k_deg(const int* __restrict__ dst, float* deg) {
    int e = blockIdx.x * blockDim.x + threadIdx.x;
    if (e < N_EDGES) atomicAdd(&deg[dst[e]], 1.0f);
}

__global__ void k_dinv(float* deg, int* cnt) {
    int i = blockIdx.x * blockDim.x + threadIdx.x;
    if (i < N_NODES) {
        float d = deg[i];
        deg[i] = rsqrtf(d);          // deg buffer becomes dinv
        cnt[i] = (int)d - 1;         // incoming non-self edges
    }
}

// ---------------- CSR build: two-level exclusive scan ----------------
__global__ void k_scan1(const int* __restrict__ cnt, int* row_ptr, int* blockSums) {
    __shared__ int s[256];
    int t = threadIdx.x;
    int i = blockIdx.x * 256 + t;
    int v = (i < N_NODES) ? cnt[i] : 0;
    s[t] = v; __syncthreads();
    for (int off = 1; off < 256; off <<= 1) {
        int x = (t >= off) ? s[t - off] : 0;
        __syncthreads();
        s[t] += x;
        __syncthreads();
    }
    if (i < N_NODES) row_ptr[i] = s[t] - v;          // exclusive within block
    if (t == 255) blockSums[blockIdx.x] = s[255];
}

__global__ void k_scan2(int* blockSums) {
    __shared__ int s[256];
    int t = threadIdx.x;
    int v = (t < SCAN_BLOCKS) ? blockSums[t] : 0;
    s[t] = v; __syncthreads();
    for (int off = 1; off < 256; off <<= 1) {
        int x = (t >= off) ? s[t - off] : 0;
        __syncthreads();
        s[t] += x;
        __syncthreads();
    }
    if (t < SCAN_BLOCKS) blockSums[t] = s[t] - v;    // exclusive
}

__global__ void k_scan3(int* row_ptr, const int* __restrict__ blockSums, int* cursor) {
    int i = blockIdx.x * blockDim.x + threadIdx.x;
    if (i < N_NODES) {
        int rp = row_ptr[i] + blockSums[i >> 8];
        row_ptr[i] = rp;
        cursor[i] = rp;
    }
    if (i == 0) row_ptr[N_NODES] = N_EDGES;
}

__global__ void k_scatter(const int* __restrict__ src, const int* __restrict__ dst,
                          int* cursor, int* csr_src) {
    int e = blockIdx.x * blockDim.x + threadIdx.x;
    if (e < N_EDGES) {
        int d = dst[e];
        int pos = atomicAdd(&cursor[d], 1);
        csr_src[pos] = src[e];
    }
}

// ---------------- aggregate (pre-transform, fp32 input, D=5) ----------------
__global__ void k_agg5(const float* __restrict__ h, const int* __restrict__ row_ptr,
                       const int* __restrict__ csr_src,
                       const float* __restrict__ dinv, float* __restrict__ out) {
    int t = threadIdx.x;
    int f = t & 7;
    int g = t >> 3;
    int node = blockIdx.x * 32 + g;
    if (node >= N_NODES || f >= 5) return;
    float di = dinv[node];
    float acc = di * h[node * 5 + f];
    int e0 = row_ptr[node], e1 = row_ptr[node + 1];
    for (int e = e0; e < e1; e++) {
        int s = csr_src[e];
        acc += dinv[s] * h[s * 5 + f];
    }
    out[node * 5 + f] = di * acc;
}

// ---------------- aggregate, bf16 input: out = D^-1/2 (A+I) D^-1/2 h ----------------
// DV = D/8 threads per node, 16B (8 bf16) per thread
template<int D>
__global__ void k_aggb(const unsigned short* __restrict__ h, const int* __restrict__ row_ptr,
                       const int* __restrict__ csr_src,
                       const float* __restrict__ dinv, float* __restrict__ out) {
    constexpr int DV = D / 8;
    constexpr int G = 256 / DV;
    const uint4* h4 = (const uint4*)h;
    int t = threadIdx.x;
    int f = t % DV;
    int g = t / DV;
    int node = blockIdx.x * G + g;
    if (node >= N_NODES) return;
    float di = dinv[node];
    float selfv[8];
    bf8_unpack(h4[(size_t)node * DV + f], selfv);
    float acc0[8], acc1[8];
    #pragma unroll
    for (int i = 0; i < 8; i++) { acc0[i] = di * selfv[i]; acc1[i] = 0.0f; }
    int e0 = row_ptr[node], e1 = row_ptr[node + 1];
    int e = e0;
    for (; e + 1 < e1; e += 2) {
        int s0 = csr_src[e], s1 = csr_src[e + 1];
        float w0 = dinv[s0], w1 = dinv[s1];
        uint4 u0 = h4[(size_t)s0 * DV + f];
        uint4 u1 = h4[(size_t)s1 * DV + f];
        float t0[8], t1[8];
        bf8_unpack(u0, t0);
        bf8_unpack(u1, t1);
        #pragma unroll
        for (int i = 0; i < 8; i++) { acc0[i] += w0 * t0[i]; acc1[i] += w1 * t1[i]; }
    }
    if (e < e1) {
        int s0 = csr_src[e];
        float w0 = dinv[s0];
        float t0[8];
        bf8_unpack(h4[(size_t)s0 * DV + f], t0);
        #pragma unroll
        for (int i = 0; i < 8; i++) acc0[i] += w0 * t0[i];
    }
    float4 o0, o1;
    o0.x = di * (acc0[0] + acc1[0]); o0.y = di * (acc0[1] + acc1[1]);
    o0.z = di * (acc0[2] + acc1[2]); o0.w = di * (acc0[3] + acc1[3]);
    o1.x = di * (acc0[4] + acc1[4]); o1.y = di * (acc0[5] + acc1[5]);
    o1.z = di * (acc0[6] + acc1[6]); o1.w = di * (acc0[7] + acc1[7]);
    float4* out4 = (float4*)out;
    out4[(size_t)node * (D / 4) + f * 2]     = o0;
    out4[(size_t)node * (D / 4) + f * 2 + 1] = o1;
}

// ---------------- layer-1 matmul (K=5): bf16 out = relu(Hin @ W + b) ----------------
template<int DIN, int DOUT>
__global__ void k_matmul(const float* __restrict__ Hin, const float* __restrict__ W,
                         const float* __restrict__ bias, unsigned short* __restrict__ Hout) {
    constexpr int G = 256 / DOUT;        // column-groups per block
    constexpr int ROWS = 16;             // rows per group
    constexpr int RPB = G * ROWS;        // rows per block
    __shared__ float lds[RPB * DIN];
    int t = threadIdx.x;
    int row0 = blockIdx.x * RPB;
    const int base = row0 * DIN;
    const int lim = N_NODES * DIN - base;
    for (int idx = t; idx < RPB * DIN; idx += 256)
        lds[idx] = (idx < lim) ? Hin[base + idx] : 0.0f;
    __syncthreads();
    int j = t % DOUT;
    int g = t / DOUT;
    float b = bias[j];
    float acc[ROWS];
    #pragma unroll
    for (int r = 0; r < ROWS; r++) acc[r] = 0.0f;
    for (int k = 0; k < DIN; k++) {
        float w = W[k * DOUT + j];
        #pragma unroll
        for (int r = 0; r < ROWS; r++)
            acc[r] += lds[(g * ROWS + r) * DIN + k] * w;
    }
    #pragma unroll
    for (int r = 0; r < ROWS; r++) {
        int gr = row0 + g * ROWS + r;
        if (gr < N_NODES) {
            float v = acc[r] + b;
            Hout[gr * DOUT + j] = f2bf(v > 0.0f ? v : 0.0f);
        }
    }
}

// ---------------- register-blocked GEMM: relu(A @ W + b), fp32 or bf16 out ----------------
template<int DIN, int DOUT, bool OBF>
__global__ __launch_bounds__(256) void k_gemm(const float* __restrict__ A,
                                              const float* __restrict__ W,
                                              const float* __restrict__ bias,
                                              void* __restrict__ Cv) {
    constexpr int BM = 128, BN = 64, BK = 32;
    __shared__ float As[BK][BM + 4];
    __shared__ float Ws[BK][BN + 4];
    int t  = threadIdx.x;
    int tx = t & 15;          // 0..15 -> col group (4 cols)
    int ty = t >> 4;          // 0..15 -> row group (8 rows)
    int row0 = blockIdx.y * BM;
    int n0   = blockIdx.x * BN;

    float acc[8][4];
    #pragma unroll
    for (int i = 0; i < 8; i++)
        #pragma unroll
        for (int j = 0; j < 4; j++) acc[i][j] = 0.0f;

    for (int k0 = 0; k0 < DIN; k0 += BK) {
        #pragma unroll
        for (int q = 0; q < 4; q++) {
            int r  = q * 32 + (t >> 3);
            int c4 = t & 7;
            int gr = row0 + r;
            float4 v = make_float4(0.f, 0.f, 0.f, 0.f);
            if (gr < N_NODES) v = *(const float4*)&A[(size_t)gr * DIN + k0 + c4 * 4];
            As[c4 * 4 + 0][r] = v.x;
            As[c4 * 4 + 1][r] = v.y;
            As[c4 * 4 + 2][r] = v.z;
            As[c4 * 4 + 3][r] = v.w;
        }
        #pragma unroll
        for (int p = 0; p < 2; p++) {
            int idx = t + 256 * p;
            int k   = idx >> 4;
            int c4  = idx & 15;
            float4 v = *(const float4*)&W[(size_t)(k0 + k) * DOUT + n0 + c4 * 4];
            *(float4*)&Ws[k][c4 * 4] = v;
        }
        __syncthreads();
        #pragma unroll
        for (int k = 0; k < BK; k++) {
            float4 a0 = *(const float4*)&As[k][ty * 8];
            float4 a1 = *(const float4*)&As[k][ty * 8 + 4];
            float4 w  = *(const float4*)&Ws[k][tx * 4];
            float ar[8] = {a0.x, a0.y, a0.z, a0.w, a1.x, a1.y, a1.z, a1.w};
            float wr[4] = {w.x, w.y, w.z, w.w};
            #pragma unroll
            for (int i = 0; i < 8; i++)
                #pragma unroll
                for (int j = 0; j < 4; j++)
                    acc[i][j] += ar[i] * wr[j];
        }
        __syncthreads();
    }

    float4 b = *(const float4*)&bias[n0 + tx * 4];
    float br[4] = {b.x, b.y, b.z, b.w};
    #pragma unroll
    for (int i = 0; i < 8; i++) {
        int gr = row0 + ty * 8 + i;
        if (gr < N_NODES) {
            float v0 = fmaxf(acc[i][0] + br[0], 0.f);
            float v1 = fmaxf(acc[i][1] + br[1], 0.f);
            float v2 = fmaxf(acc[i][2] + br[2], 0.f);
            float v3 = fmaxf(acc[i][3] + br[3], 0.f);
            if constexpr (OBF) {
                ushort4 o;
                o.x = f2bf(v0); o.y = f2bf(v1); o.z = f2bf(v2); o.w = f2bf(v3);
                ((ushort4*)Cv)[((size_t)gr * DOUT + n0) / 4 + tx] = o;
            } else {
                float4 o = make_float4(v0, v1, v2, v3);
                *(float4*)&((float*)Cv)[(size_t)gr * DOUT + n0 + tx * 4] = o;
            }
        }
    }
}

// ---------------- graph counts via binary search (batch is sorted) ----------------
__global__ void k_counts_bs(const int* __restrict__ batch, float* gcount) {
    int g = threadIdx.x;
    if (g >= N_GRAPHS) return;
    int lo = 0, hi = N_NODES;
    while (lo < hi) { int m = (lo + hi) >> 1; if (batch[m] < g) lo = m + 1; else hi = m; }
    int start = lo;
    lo = 0; hi = N_NODES;
    while (lo < hi) { int m = (lo + hi) >> 1; if (batch[m] < g + 1) lo = m + 1; else hi = m; }
    gcount[g] = (float)(lo - start);
}

// ---------------- pooling ----------------
#define POOL_CHUNK 64
__global__ void k_pool(const float* __restrict__ h, const int* __restrict__ batch,
                       float* pooled) {
    int t = threadIdx.x;                 // feature 0..255
    int n0 = blockIdx.x * POOL_CHUNK;
    int n1 = n0 + POOL_CHUNK; if (n1 > N_NODES) n1 = N_NODES;
    float acc = 0.0f;
    int cur = batch[n0];
    for (int i = n0; i < n1; i++) {
        int g = batch[i];
        if (g != cur) {
            atomicAdd(&pooled[cur * 256 + t], acc);
            acc = 0.0f; cur = g;
        }
        acc += h[i * 256 + t];
    }
    atomicAdd(&pooled[cur * 256 + t], acc);
}

// ---------------- FC + log_softmax (one wave per graph) ----------------
__global__ void k_final(const float* __restrict__ pooled, const float* __restrict__ gcount,
                        const float* __restrict__ fcW, const float* __restrict__ fcb,
                        float* __restrict__ out) {
    int g = blockIdx.x;
    int t = threadIdx.x;                 // 0..63
    float p[4];
    #pragma unroll
    for (int m = 0; m < 4; m++) p[m] = pooled[g * 256 + t + 64 * m];
    float inv = 1.0f / fmaxf(gcount[g], 1.0f);
    float logits[NUM_CLASSES];
    #pragma unroll
    for (int j = 0; j < NUM_CLASSES; j++) {
        float s = 0.0f;
        #pragma unroll
        for (int m = 0; m < 4; m++) s += p[m] * fcW[(t + 64 * m) * NUM_CLASSES + j];
        for (int off = 32; off > 0; off >>= 1) s += __shfl_xor(s, off);
        logits[j] = s * inv + fcb[j];
    }
    float mx = logits[0];
    #pragma unroll
    for (int j = 1; j < NUM_CLASSES; j++) mx = fmaxf(mx, logits[j]);
    float se = 0.0f;
    #pragma unroll
    for (int j = 0; j < NUM_CLASSES; j++) se += expf(logits[j] - mx);
    float lse = mx + logf(se);
    if (t < NUM_CLASSES) out[g * NUM_CLASSES + t] = logits[t] - lse;
}

extern "C" void kernel_launch(void* const* d_in, const int* in_sizes, int n_in,
                              void* d_out, int out_size, void* d_ws, size_t ws_size,
                              hipStream_t stream) {
    const float* x     = (const float*)d_in[0];
    const int*   ei    = (const int*)d_in[1];
    const int*   src   = ei;
    const int*   dst   = ei + N_EDGES;
    const int*   batch = (const int*)d_in[2];
    const float* W1 = (const float*)d_in[3];  const float* b1 = (const float*)d_in[4];
    const float* W2 = (const float*)d_in[5];  const float* b2 = (const float*)d_in[6];
    const float* W3 = (const float*)d_in[7];  const float* b3 = (const float*)d_in[8];
    const float* W4 = (const float*)d_in[9];  const float* b4 = (const float*)d_in[10];
    const float* fcW = (const float*)d_in[11]; const float* fcb = (const float*)d_in[12];
    float* out = (float*)d_out;

    char* ws = (char*)d_ws;
    float* bufA     = (float*)ws; ws += (size_t)N_NODES * 256 * 4;   // agg out (fp32)
    float* bufB     = (float*)ws; ws += (size_t)N_NODES * 256 * 4;   // h (bf16 L1-3, fp32 L4)
    float* dinv     = (float*)ws; ws += (size_t)N_NODES * 4;         // deg -> dinv
    int*   cnt      = (int*)ws;   ws += (size_t)N_NODES * 4;
    int*   row_ptr  = (int*)ws;   ws += (size_t)(N_NODES + 4) * 4;
    int*   cursor   = (int*)ws;   ws += (size_t)N_NODES * 4;
    int*   blockSums= (int*)ws;   ws += 256 * 4;
    int*   csr_src  = (int*)ws;   ws += (size_t)N_EDGES * 4;
    float* pooled   = (float*)ws; ws += (size_t)N_GRAPHS * 256 * 4;
    float* gcount   = (float*)ws; ws += (size_t)N_GRAPHS * 4;
    unsigned short* hb = (unsigned short*)bufB;

    const int TB = 256;
    // normalization + CSR
    k_init<<<(N_NODES + TB - 1) / TB, TB, 0, stream>>>(dinv, pooled);
    k_deg<<<(N_EDGES + TB - 1) / TB, TB, 0, stream>>>(dst, dinv);
    k_dinv<<<SCAN_BLOCKS, TB, 0, stream>>>(dinv, cnt);
    k_scan1<<<SCAN_BLOCKS, TB, 0, stream>>>(cnt, row_ptr, blockSums);
    k_scan2<<<1, TB, 0, stream>>>(blockSums);
    k_scan3<<<SCAN_BLOCKS, TB, 0, stream>>>(row_ptr, blockSums, cursor);
    k_scatter<<<(N_EDGES + TB - 1) / TB, TB, 0, stream>>>(src, dst, cursor, csr_src);
    k_counts_bs<<<1, 64, 0, stream>>>(batch, gcount);

    const int NBM = (N_NODES + 127) / 128;   // 391
    // layer 1: agg(x)[5] -> mm 5->32 (bf16 out)
    k_agg5<<<(N_NODES + 31) / 32, TB, 0, stream>>>(x, row_ptr, csr_src, dinv, bufA);
    k_matmul<5, 32><<<(N_NODES + 127) / 128, TB, 0, stream>>>(bufA, W1, b1, hb);
    // layer 2: agg[32] bf16 -> gemm 32->64 (bf16 out)
    k_aggb<32><<<(N_NODES + 63) / 64, TB, 0, stream>>>(hb, row_ptr, csr_src, dinv, bufA);
    k_gemm<32, 64, true><<<dim3(1, NBM), TB, 0, stream>>>(bufA, W2, b2, hb);
    // layer 3: agg[64] bf16 -> gemm 64->128 (bf16 out)
    k_aggb<64><<<(N_NODES + 31) / 32, TB, 0, stream>>>(hb, row_ptr, csr_src, dinv, bufA);
    k_gemm<64, 128, true><<<dim3(2, NBM), TB, 0, stream>>>(bufA, W3, b3, hb);
    // layer 4: agg[128] bf16 -> gemm 128->256 (fp32 out)
    k_aggb<128><<<(N_NODES + 15) / 16, TB, 0, stream>>>(hb, row_ptr, csr_src, dinv, bufA);
    k_gemm<128, 256, false><<<dim3(4, NBM), TB, 0, stream>>>(bufA, W4, b4, bufB);

    // pooling + classifier
    k_pool<<<(N_NODES + POOL_CHUNK - 1) / POOL_CHUNK, TB, 0, stream>>>(bufB, batch, pooled);
    k_final<<<N_GRAPHS, 64, 0, stream>>>(pooled, gcount, fcW, fcb, out);
}

// Round 5
// 353.061 us; speedup vs baseline: 3.8175x; 1.1217x over previous
//
#include <hip/hip_runtime.h>
#include <hip/hip_bf16.h>
#include <math.h>

#define N_NODES 50000
#define N_EDGES 800000
#define N_GRAPHS 64
#define NUM_CLASSES 10
#define SCAN_BLOCKS ((N_NODES + 255) / 256)   // 196
#define MTILES ((N_NODES + 15) / 16)          // 3125

typedef __attribute__((ext_vector_type(8))) short bf16x8;
typedef __attribute__((ext_vector_type(4))) float f32x4;

// fp32 -> bf16 round-to-nearest-even (values finite)
__device__ inline unsigned short f2bf(float f) {
    unsigned int u = __float_as_uint(f);
    u += 0x7fffu + ((u >> 16) & 1u);
    return (unsigned short)(u >> 16);
}
__device__ inline float bf2f(unsigned short v) {
    return __uint_as_float((unsigned int)v << 16);
}
__device__ inline void bf8_unpack(uint4 v, float* o) {
    o[0] = __uint_as_float(v.x << 16); o[1] = __uint_as_float(v.x & 0xffff0000u);
    o[2] = __uint_as_float(v.y << 16); o[3] = __uint_as_float(v.y & 0xffff0000u);
    o[4] = __uint_as_float(v.z << 16); o[5] = __uint_as_float(v.z & 0xffff0000u);
    o[6] = __uint_as_float(v.w << 16); o[7] = __uint_as_float(v.w & 0xffff0000u);
}
__device__ inline unsigned int pack2(float a, float b) {
    return (unsigned int)f2bf(a) | ((unsigned int)f2bf(b) << 16);
}

// ---------------- init ----------------
__global__ void k_init(float* deg, float* pooled) {
    int i = blockIdx.x * blockDim.x + threadIdx.x;
    if (i < N_NODES) deg[i] = 1.0f;                 // self loop
    if (i < N_GRAPHS * 256) pooled[i] = 0.0f;
}

// ---------------- degree ----------------
__global__ void k_deg(const int* __restrict__ dst, float* deg) {
    int e = blockIdx.x * blockDim.x + threadIdx.x;
    if (e < N_EDGES) atomicAdd(&deg[dst[e]], 1.0f);
}

__global__ void k_dinv(float* deg, int* cnt) {
    int i = blockIdx.x * blockDim.x + threadIdx.x;
    if (i < N_NODES) {
        float d = deg[i];
        deg[i] = rsqrtf(d);          // deg buffer becomes dinv
        cnt[i] = (int)d - 1;         // incoming non-self edges
    }
}

// ---------------- CSR build: two-level exclusive scan ----------------
__global__ void k_scan1(const int* __restrict__ cnt, int* row_ptr, int* blockSums) {
    __shared__ int s[256];
    int t = threadIdx.x;
    int i = blockIdx.x * 256 + t;
    int v = (i < N_NODES) ? cnt[i] : 0;
    s[t] = v; __syncthreads();
    for (int off = 1; off < 256; off <<= 1) {
        int x = (t >= off) ? s[t - off] : 0;
        __syncthreads();
        s[t] += x;
        __syncthreads();
    }
    if (i < N_NODES) row_ptr[i] = s[t] - v;
    if (t == 255) blockSums[blockIdx.x] = s[255];
}

__global__ void k_scan2(int* blockSums) {
    __shared__ int s[256];
    int t = threadIdx.x;
    int v = (t < SCAN_BLOCKS) ? blockSums[t] : 0;
    s[t] = v; __syncthreads();
    for (int off = 1; off < 256; off <<= 1) {
        int x = (t >= off) ? s[t - off] : 0;
        __syncthreads();
        s[t] += x;
        __syncthreads();
    }
    if (t < SCAN_BLOCKS) blockSums[t] = s[t] - v;
}

__global__ void k_scan3(int* row_ptr, const int* __restrict__ blockSums, int* cursor) {
    int i = blockIdx.x * blockDim.x + threadIdx.x;
    if (i < N_NODES) {
        int rp = row_ptr[i] + blockSums[i >> 8];
        row_ptr[i] = rp;
        cursor[i] = rp;
    }
    if (i == 0) row_ptr[N_NODES] = N_EDGES;
}

__global__ void k_scatter(const int* __restrict__ src, const int* __restrict__ dst,
                          int* cursor, int* csr_src) {
    int e = blockIdx.x * blockDim.x + threadIdx.x;
    if (e < N_EDGES) {
        int d = dst[e];
        int pos = atomicAdd(&cursor[d], 1);
        csr_src[pos] = src[e];
    }
}

// ---------------- aggregate (fp32 input, D=5) ----------------
__global__ void k_agg5(const float* __restrict__ h, const int* __restrict__ row_ptr,
                       const int* __restrict__ csr_src,
                       const float* __restrict__ dinv, float* __restrict__ out) {
    int t = threadIdx.x;
    int f = t & 7;
    int g = t >> 3;
    int node = blockIdx.x * 32 + g;
    if (node >= N_NODES || f >= 5) return;
    float di = dinv[node];
    float acc = di * h[node * 5 + f];
    int e0 = row_ptr[node], e1 = row_ptr[node + 1];
    for (int e = e0; e < e1; e++) {
        int s = csr_src[e];
        acc += dinv[s] * h[s * 5 + f];
    }
    out[node * 5 + f] = di * acc;
}

// ---------------- aggregate, bf16 in -> bf16 out ----------------
template<int D>
__global__ void k_aggb(const unsigned short* __restrict__ h, const int* __restrict__ row_ptr,
                       const int* __restrict__ csr_src,
                       const float* __restrict__ dinv, unsigned short* __restrict__ out) {
    constexpr int DV = D / 8;
    constexpr int G = 256 / DV;
    const uint4* h4 = (const uint4*)h;
    int t = threadIdx.x;
    int f = t % DV;
    int g = t / DV;
    int node = blockIdx.x * G + g;
    if (node >= N_NODES) return;
    float di = dinv[node];
    float selfv[8];
    bf8_unpack(h4[(size_t)node * DV + f], selfv);
    float acc0[8], acc1[8];
    #pragma unroll
    for (int i = 0; i < 8; i++) { acc0[i] = di * selfv[i]; acc1[i] = 0.0f; }
    int e0 = row_ptr[node], e1 = row_ptr[node + 1];
    int e = e0;
    for (; e + 1 < e1; e += 2) {
        int s0 = csr_src[e], s1 = csr_src[e + 1];
        float w0 = dinv[s0], w1 = dinv[s1];
        uint4 u0 = h4[(size_t)s0 * DV + f];
        uint4 u1 = h4[(size_t)s1 * DV + f];
        float t0[8], t1[8];
        bf8_unpack(u0, t0);
        bf8_unpack(u1, t1);
        #pragma unroll
        for (int i = 0; i < 8; i++) { acc0[i] += w0 * t0[i]; acc1[i] += w1 * t1[i]; }
    }
    if (e < e1) {
        int s0 = csr_src[e];
        float w0 = dinv[s0];
        float t0[8];
        bf8_unpack(h4[(size_t)s0 * DV + f], t0);
        #pragma unroll
        for (int i = 0; i < 8; i++) acc0[i] += w0 * t0[i];
    }
    uint4 o;
    o.x = pack2(di * (acc0[0] + acc1[0]), di * (acc0[1] + acc1[1]));
    o.y = pack2(di * (acc0[2] + acc1[2]), di * (acc0[3] + acc1[3]));
    o.z = pack2(di * (acc0[4] + acc1[4]), di * (acc0[5] + acc1[5]));
    o.w = pack2(di * (acc0[6] + acc1[6]), di * (acc0[7] + acc1[7]));
    ((uint4*)out)[(size_t)node * DV + f] = o;
}

// ---------------- layer-1 matmul (K=5): bf16 out = relu(Hin @ W + b) ----------------
template<int DIN, int DOUT>
__global__ void k_matmul(const float* __restrict__ Hin, const float* __restrict__ W,
                         const float* __restrict__ bias, unsigned short* __restrict__ Hout) {
    constexpr int G = 256 / DOUT;
    constexpr int ROWS = 16;
    constexpr int RPB = G * ROWS;
    __shared__ float lds[RPB * DIN];
    int t = threadIdx.x;
    int row0 = blockIdx.x * RPB;
    const int base = row0 * DIN;
    const int lim = N_NODES * DIN - base;
    for (int idx = t; idx < RPB * DIN; idx += 256)
        lds[idx] = (idx < lim) ? Hin[base + idx] : 0.0f;
    __syncthreads();
    int j = t % DOUT;
    int g = t / DOUT;
    float b = bias[j];
    float acc[ROWS];
    #pragma unroll
    for (int r = 0; r < ROWS; r++) acc[r] = 0.0f;
    for (int k = 0; k < DIN; k++) {
        float w = W[k * DOUT + j];
        #pragma unroll
        for (int r = 0; r < ROWS; r++)
            acc[r] += lds[(g * ROWS + r) * DIN + k] * w;
    }
    #pragma unroll
    for (int r = 0; r < ROWS; r++) {
        int gr = row0 + g * ROWS + r;
        if (gr < N_NODES) {
            float v = acc[r] + b;
            Hout[gr * DOUT + j] = f2bf(v > 0.0f ? v : 0.0f);
        }
    }
}

// ---------------- pack W (fp32, row-major KxN) into MFMA B-fragment layout ----------------
// Wp[((nt*KT+kt)*64 + lane)*8 + j] = bf16( W[(kt*32 + (lane>>4)*8 + j)*N + nt*16 + (lane&15)] )
template<int K, int N>
__global__ void k_packW(const float* __restrict__ W, unsigned short* __restrict__ Wp) {
    constexpr int KT = K / 32;
    int bid = blockIdx.x;            // nt*KT + kt
    int kt = bid % KT, nt = bid / KT;
    int l = threadIdx.x;             // 0..63
    int m = l & 15, quad = l >> 4;
    #pragma unroll
    for (int j = 0; j < 8; j++) {
        int k = kt * 32 + quad * 8 + j;
        int n = nt * 16 + m;
        Wp[((size_t)bid * 64 + l) * 8 + j] = f2bf(W[(size_t)k * N + n]);
    }
}

// ---------------- MFMA GEMM: C = relu(A @ W + b), A bf16 [M x K], Wp packed bf16 ----------------
// 4 waves/block; each wave computes 2 consecutive 16-row M-tiles x full N.
template<int K, int N, bool OBF>
__global__ __launch_bounds__(256) void k_gemm_mfma(const unsigned short* __restrict__ A,
                                                   const unsigned short* __restrict__ Wp,
                                                   const float* __restrict__ bias,
                                                   void* __restrict__ Cv) {
    constexpr int KT = K / 32, NT = N / 16;
    int wave = threadIdx.x >> 6, lane = threadIdx.x & 63;
    int wid = blockIdx.x * 4 + wave;
    int mt0 = wid * 2;
    if (mt0 >= MTILES) return;
    bool two = (mt0 + 1) < MTILES;
    int m = lane & 15, quad = lane >> 4;
    // preload A fragments (lane holds A[mt*16+m][kt*32+quad*8 .. +7], contiguous 16B)
    bf16x8 a0[KT], a1[KT];
    #pragma unroll
    for (int kt = 0; kt < KT; kt++) {
        a0[kt] = *(const bf16x8*)(A + (size_t)(mt0 * 16 + m) * K + kt * 32 + quad * 8);
        a1[kt] = *(const bf16x8*)(A + (size_t)((mt0 + 1) * 16 + m) * K + kt * 32 + quad * 8);
    }
    const bf16x8* Bp = (const bf16x8*)Wp;
    for (int nt = 0; nt < NT; nt++) {
        f32x4 c0 = {0.f, 0.f, 0.f, 0.f}, c1 = {0.f, 0.f, 0.f, 0.f};
        #pragma unroll
        for (int kt = 0; kt < KT; kt++) {
            bf16x8 b = Bp[(size_t)(nt * KT + kt) * 64 + lane];
            c0 = __builtin_amdgcn_mfma_f32_16x16x32_bf16(a0[kt], b, c0, 0, 0, 0);
            c1 = __builtin_amdgcn_mfma_f32_16x16x32_bf16(a1[kt], b, c1, 0, 0, 0);
        }
        int col = nt * 16 + m;
        float bv = bias[col];
        #pragma unroll
        for (int r = 0; r < 4; r++) {
            int row0 = mt0 * 16 + quad * 4 + r;
            float v0 = fmaxf(c0[r] + bv, 0.f);
            if constexpr (OBF) ((unsigned short*)Cv)[(size_t)row0 * N + col] = f2bf(v0);
            else               ((float*)Cv)[(size_t)row0 * N + col] = v0;
            if (two) {
                int row1 = row0 + 16;
                float v1 = fmaxf(c1[r] + bv, 0.f);
                if constexpr (OBF) ((unsigned short*)Cv)[(size_t)row1 * N + col] = f2bf(v1);
                else               ((float*)Cv)[(size_t)row1 * N + col] = v1;
            }
        }
    }
}

// ---------------- graph counts via binary search (batch is sorted) ----------------
__global__ void k_counts_bs(const int* __restrict__ batch, float* gcount) {
    int g = threadIdx.x;
    if (g >= N_GRAPHS) return;
    int lo = 0, hi = N_NODES;
    while (lo < hi) { int m = (lo + hi) >> 1; if (batch[m] < g) lo = m + 1; else hi = m; }
    int start = lo;
    lo = 0; hi = N_NODES;
    while (lo < hi) { int m = (lo + hi) >> 1; if (batch[m] < g + 1) lo = m + 1; else hi = m; }
    gcount[g] = (float)(lo - start);
}

// ---------------- pooling (bf16 h) ----------------
#define POOL_CHUNK 64
__global__ void k_poolb(const unsigned short* __restrict__ h, const int* __restrict__ batch,
                        float* pooled) {
    int t = threadIdx.x;                 // feature 0..255
    int n0 = blockIdx.x * POOL_CHUNK;
    int n1 = n0 + POOL_CHUNK; if (n1 > N_NODES) n1 = N_NODES;
    float acc = 0.0f;
    int cur = batch[n0];
    for (int i = n0; i < n1; i++) {
        int g = batch[i];
        if (g != cur) {
            atomicAdd(&pooled[cur * 256 + t], acc);
            acc = 0.0f; cur = g;
        }
        acc += bf2f(h[(size_t)i * 256 + t]);
    }
    atomicAdd(&pooled[cur * 256 + t], acc);
}

// ---------------- FC + log_softmax (one wave per graph) ----------------
__global__ void k_final(const float* __restrict__ pooled, const float* __restrict__ gcount,
                        const float* __restrict__ fcW, const float* __restrict__ fcb,
                        float* __restrict__ out) {
    int g = blockIdx.x;
    int t = threadIdx.x;                 // 0..63
    float p[4];
    #pragma unroll
    for (int m = 0; m < 4; m++) p[m] = pooled[g * 256 + t + 64 * m];
    float inv = 1.0f / fmaxf(gcount[g], 1.0f);
    float logits[NUM_CLASSES];
    #pragma unroll
    for (int j = 0; j < NUM_CLASSES; j++) {
        float s = 0.0f;
        #pragma unroll
        for (int m = 0; m < 4; m++) s += p[m] * fcW[(t + 64 * m) * NUM_CLASSES + j];
        for (int off = 32; off > 0; off >>= 1) s += __shfl_xor(s, off);
        logits[j] = s * inv + fcb[j];
    }
    float mx = logits[0];
    #pragma unroll
    for (int j = 1; j < NUM_CLASSES; j++) mx = fmaxf(mx, logits[j]);
    float se = 0.0f;
    #pragma unroll
    for (int j = 0; j < NUM_CLASSES; j++) se += expf(logits[j] - mx);
    float lse = mx + logf(se);
    if (t < NUM_CLASSES) out[g * NUM_CLASSES + t] = logits[t] - lse;
}

extern "C" void kernel_launch(void* const* d_in, const int* in_sizes, int n_in,
                              void* d_out, int out_size, void* d_ws, size_t ws_size,
                              hipStream_t stream) {
    const float* x     = (const float*)d_in[0];
    const int*   ei    = (const int*)d_in[1];
    const int*   src   = ei;
    const int*   dst   = ei + N_EDGES;
    const int*   batch = (const int*)d_in[2];
    const float* W1 = (const float*)d_in[3];  const float* b1 = (const float*)d_in[4];
    const float* W2 = (const float*)d_in[5];  const float* b2 = (const float*)d_in[6];
    const float* W3 = (const float*)d_in[7];  const float* b3 = (const float*)d_in[8];
    const float* W4 = (const float*)d_in[9];  const float* b4 = (const float*)d_in[10];
    const float* fcW = (const float*)d_in[11]; const float* fcb = (const float*)d_in[12];
    float* out = (float*)d_out;

    char* ws = (char*)d_ws;
    float* bufA     = (float*)ws; ws += (size_t)N_NODES * 256 * 4;   // agg out (fp32 L1 / bf16 L2-4)
    float* bufB     = (float*)ws; ws += (size_t)N_NODES * 256 * 4;   // h (bf16)
    float* dinv     = (float*)ws; ws += (size_t)N_NODES * 4;
    int*   cnt      = (int*)ws;   ws += (size_t)N_NODES * 4;
    int*   row_ptr  = (int*)ws;   ws += (size_t)(N_NODES + 4) * 4;
    int*   cursor   = (int*)ws;   ws += (size_t)N_NODES * 4;
    int*   blockSums= (int*)ws;   ws += 256 * 4;
    int*   csr_src  = (int*)ws;   ws += (size_t)N_EDGES * 4;
    float* pooled   = (float*)ws; ws += (size_t)N_GRAPHS * 256 * 4;
    float* gcount   = (float*)ws; ws += (size_t)N_GRAPHS * 4;
    unsigned short* wp2 = (unsigned short*)ws; ws += 32 * 64 * 2;
    unsigned short* wp3 = (unsigned short*)ws; ws += 64 * 128 * 2;
    unsigned short* wp4 = (unsigned short*)ws; ws += 128 * 256 * 2;
    unsigned short* hb = (unsigned short*)bufB;   // bf16 h
    unsigned short* ab = (unsigned short*)bufA;   // bf16 agg out

    const int TB = 256;
    // normalization + CSR + weight packing
    k_init<<<(N_NODES + TB - 1) / TB, TB, 0, stream>>>(dinv, pooled);
    k_packW<32, 64><<<1 * 4, 64, 0, stream>>>(W2, wp2);
    k_packW<64, 128><<<2 * 8, 64, 0, stream>>>(W3, wp3);
    k_packW<128, 256><<<4 * 16, 64, 0, stream>>>(W4, wp4);
    k_deg<<<(N_EDGES + TB - 1) / TB, TB, 0, stream>>>(dst, dinv);
    k_dinv<<<SCAN_BLOCKS, TB, 0, stream>>>(dinv, cnt);
    k_scan1<<<SCAN_BLOCKS, TB, 0, stream>>>(cnt, row_ptr, blockSums);
    k_scan2<<<1, TB, 0, stream>>>(blockSums);
    k_scan3<<<SCAN_BLOCKS, TB, 0, stream>>>(row_ptr, blockSums, cursor);
    k_scatter<<<(N_EDGES + TB - 1) / TB, TB, 0, stream>>>(src, dst, cursor, csr_src);
    k_counts_bs<<<1, 64, 0, stream>>>(batch, gcount);

    const int GEMM_BLOCKS = ((MTILES + 1) / 2 + 3) / 4;   // 391
    // layer 1: agg(x)[5] -> mm 5->32 (bf16 out)
    k_agg5<<<(N_NODES + 31) / 32, TB, 0, stream>>>(x, row_ptr, csr_src, dinv, bufA);
    k_matmul<5, 32><<<(N_NODES + 127) / 128, TB, 0, stream>>>(bufA, W1, b1, hb);
    // layer 2: agg[32] -> mfma gemm 32->64
    k_aggb<32><<<(N_NODES + 63) / 64, TB, 0, stream>>>(hb, row_ptr, csr_src, dinv, ab);
    k_gemm_mfma<32, 64, true><<<GEMM_BLOCKS, TB, 0, stream>>>(ab, wp2, b2, hb);
    // layer 3: agg[64] -> mfma gemm 64->128
    k_aggb<64><<<(N_NODES + 31) / 32, TB, 0, stream>>>(hb, row_ptr, csr_src, dinv, ab);
    k_gemm_mfma<64, 128, true><<<GEMM_BLOCKS, TB, 0, stream>>>(ab, wp3, b3, hb);
    // layer 4: agg[128] -> mfma gemm 128->256 (bf16 out)
    k_aggb<128><<<(N_NODES + 15) / 16, TB, 0, stream>>>(hb, row_ptr, csr_src, dinv, ab);
    k_gemm_mfma<128, 256, true><<<GEMM_BLOCKS, TB, 0, stream>>>(ab, wp4, b4, hb);

    // pooling + classifier
    k_poolb<<<(N_NODES + POOL_CHUNK - 1) / POOL_CHUNK, TB, 0, stream>>>(hb, batch, pooled);
    k_final<<<N_GRAPHS, 64, 0, stream>>>(pooled, gcount, fcW, fcb, out);
}

// Round 6
// 277.426 us; speedup vs baseline: 4.8583x; 1.2726x over previous
//
#include <hip/hip_runtime.h>
#include <hip/hip_bf16.h>
#include <math.h>

#define N_NODES 50000
#define N_EDGES 800000
#define N_GRAPHS 64
#define NUM_CLASSES 10
#define MTILES ((N_NODES + 15) / 16)          // 3125
#define BIN_W 256
#define NBINS ((N_NODES + BIN_W - 1) / BIN_W) // 196
#define CHUNK 4096
#define NCHUNKS ((N_EDGES + CHUNK - 1) / CHUNK) // 196

typedef __attribute__((ext_vector_type(8))) short bf16x8;
typedef __attribute__((ext_vector_type(4))) float f32x4;

// fp32 -> bf16 round-to-nearest-even (values finite)
__device__ inline unsigned short f2bf(float f) {
    unsigned int u = __float_as_uint(f);
    u += 0x7fffu + ((u >> 16) & 1u);
    return (unsigned short)(u >> 16);
}
__device__ inline float bf2f(unsigned short v) {
    return __uint_as_float((unsigned int)v << 16);
}
__device__ inline void bf8_unpack(uint4 v, float* o) {
    o[0] = __uint_as_float(v.x << 16); o[1] = __uint_as_float(v.x & 0xffff0000u);
    o[2] = __uint_as_float(v.y << 16); o[3] = __uint_as_float(v.y & 0xffff0000u);
    o[4] = __uint_as_float(v.z << 16); o[5] = __uint_as_float(v.z & 0xffff0000u);
    o[6] = __uint_as_float(v.w << 16); o[7] = __uint_as_float(v.w & 0xffff0000u);
}
__device__ inline unsigned int pack2(float a, float b) {
    return (unsigned int)f2bf(a) | ((unsigned int)f2bf(b) << 16);
}

// ---------------- init ----------------
__global__ void k_init(float* pooled, int* bin_cnt) {
    int i = blockIdx.x * blockDim.x + threadIdx.x;
    if (i < N_GRAPHS * 256) pooled[i] = 0.0f;
    if (i < NBINS) bin_cnt[i] = 0;
}

// ---------------- binned CSR build ----------------
// pass 0: global bin histogram (bin = dst >> 8)
__global__ void k_hist(const int* __restrict__ dst, int* bin_cnt) {
    __shared__ int h[NBINS];
    for (int i = threadIdx.x; i < NBINS; i += 256) h[i] = 0;
    __syncthreads();
    int idx = blockIdx.x * 256 + threadIdx.x;
    int stride = gridDim.x * 256;
    for (int e = idx; e < N_EDGES; e += stride)
        atomicAdd(&h[dst[e] >> 8], 1);
    __syncthreads();
    for (int i = threadIdx.x; i < NBINS; i += 256)
        if (h[i]) atomicAdd(&bin_cnt[i], h[i]);
}

// pass 1: scan bins (1 block)
__global__ void k_binscan(const int* __restrict__ bin_cnt, int* bin_start, int* bin_cursor) {
    __shared__ int s[256];
    int t = threadIdx.x;
    int v = (t < NBINS) ? bin_cnt[t] : 0;
    s[t] = v; __syncthreads();
    for (int off = 1; off < 256; off <<= 1) {
        int x = (t >= off) ? s[t - off] : 0;
        __syncthreads();
        s[t] += x;
        __syncthreads();
    }
    if (t < NBINS) { bin_start[t] = s[t] - v; bin_cursor[t] = s[t] - v; }
    if (t == 0) bin_start[NBINS] = N_EDGES;
}

// pass 2: bin-scatter with LDS staging. packed = (dst&255)<<24 | src  (src < 2^17)
__global__ __launch_bounds__(256) void k_binscatter(const int* __restrict__ src,
                                                    const int* __restrict__ dst,
                                                    int* bin_cursor,
                                                    unsigned int* __restrict__ binned) {
    __shared__ int hist[NBINS];
    __shared__ int off[NBINS];
    __shared__ int bump[NBINS];
    __shared__ int gbase[NBINS];
    __shared__ unsigned int stage[CHUNK];
    __shared__ unsigned char sbin[CHUNK];
    int t = threadIdx.x;
    int base = blockIdx.x * CHUNK;
    int total = N_EDGES - base; if (total > CHUNK) total = CHUNK;
    for (int i = t; i < NBINS; i += 256) { hist[i] = 0; bump[i] = 0; }
    __syncthreads();
    int es[16], ed[16];
    #pragma unroll
    for (int i = 0; i < 16; i++) {
        int e = base + t + i * 256;
        if (e < N_EDGES) { es[i] = src[e]; ed[i] = dst[e]; }
        else ed[i] = -1;
    }
    #pragma unroll
    for (int i = 0; i < 16; i++)
        if (ed[i] >= 0) atomicAdd(&hist[ed[i] >> 8], 1);
    __syncthreads();
    // exclusive scan of hist -> off (256-thread scan over NBINS entries)
    {
        __shared__ int s[256];
        int v = (t < NBINS) ? hist[t] : 0;
        s[t] = v; __syncthreads();
        for (int o = 1; o < 256; o <<= 1) {
            int x = (t >= o) ? s[t - o] : 0;
            __syncthreads();
            s[t] += x;
            __syncthreads();
        }
        if (t < NBINS) off[t] = s[t] - v;
    }
    __syncthreads();
    // reserve global ranges
    if (t < NBINS && hist[t] > 0) gbase[t] = atomicAdd(&bin_cursor[t], hist[t]);
    // stage edges grouped by bin
    #pragma unroll
    for (int i = 0; i < 16; i++) {
        if (ed[i] >= 0) {
            int b = ed[i] >> 8;
            int lpos = off[b] + atomicAdd(&bump[b], 1);
            stage[lpos] = ((unsigned int)(ed[i] & 255) << 24) | (unsigned int)es[i];
            sbin[lpos] = (unsigned char)b;
        }
    }
    __syncthreads();
    // write out: contiguous per-bin bursts
    for (int j = t; j < total; j += 256) {
        int b = sbin[j];
        binned[gbase[b] + (j - off[b])] = stage[j];
    }
}

// pass 3: per-bin CSR finalize: deg/dinv/row_ptr + local scatter
__global__ __launch_bounds__(256) void k_csr(const unsigned int* __restrict__ binned,
                                             const int* __restrict__ bin_start,
                                             int* __restrict__ row_ptr,
                                             float* __restrict__ dinv,
                                             int* __restrict__ csr_src) {
    __shared__ int deg[BIN_W];
    __shared__ int off[BIN_W];
    __shared__ int bump[BIN_W];
    int b = blockIdx.x;
    int t = threadIdx.x;
    deg[t] = 0; bump[t] = 0;
    __syncthreads();
    int e0 = bin_start[b], e1 = bin_start[b + 1];
    for (int e = e0 + t; e < e1; e += 256)
        atomicAdd(&deg[binned[e] >> 24], 1);
    __syncthreads();
    // exclusive scan deg -> off
    {
        __shared__ int s[256];
        int v = deg[t];
        s[t] = v; __syncthreads();
        for (int o = 1; o < 256; o <<= 1) {
            int x = (t >= o) ? s[t - o] : 0;
            __syncthreads();
            s[t] += x;
            __syncthreads();
        }
        off[t] = s[t] - v;
    }
    __syncthreads();
    int node = b * BIN_W + t;
    if (node < N_NODES) {
        row_ptr[node] = e0 + off[t];
        dinv[node] = rsqrtf((float)(deg[t] + 1));
    }
    if (b == 0 && t == 0) row_ptr[N_NODES] = N_EDGES;
    for (int e = e0 + t; e < e1; e += 256) {
        unsigned int v = binned[e];
        int dl = v >> 24;
        int pos = e0 + off[dl] + atomicAdd(&bump[dl], 1);
        csr_src[pos] = (int)(v & 0x1ffffu);
    }
}

// ---------------- aggregate (fp32 input, D=5) ----------------
__global__ void k_agg5(const float* __restrict__ h, const int* __restrict__ row_ptr,
                       const int* __restrict__ csr_src,
                       const float* __restrict__ dinv, float* __restrict__ out) {
    int t = threadIdx.x;
    int f = t & 7;
    int g = t >> 3;
    int node = blockIdx.x * 32 + g;
    if (node >= N_NODES || f >= 5) return;
    float di = dinv[node];
    float acc = di * h[node * 5 + f];
    int e0 = row_ptr[node], e1 = row_ptr[node + 1];
    for (int e = e0; e < e1; e++) {
        int s = csr_src[e];
        acc += dinv[s] * h[s * 5 + f];
    }
    out[node * 5 + f] = di * acc;
}

// ---------------- aggregate, bf16 in -> bf16 out ----------------
template<int D>
__global__ void k_aggb(const unsigned short* __restrict__ h, const int* __restrict__ row_ptr,
                       const int* __restrict__ csr_src,
                       const float* __restrict__ dinv, unsigned short* __restrict__ out) {
    constexpr int DV = D / 8;
    constexpr int G = 256 / DV;
    const uint4* h4 = (const uint4*)h;
    int t = threadIdx.x;
    int f = t % DV;
    int g = t / DV;
    int node = blockIdx.x * G + g;
    if (node >= N_NODES) return;
    float di = dinv[node];
    float selfv[8];
    bf8_unpack(h4[(size_t)node * DV + f], selfv);
    float acc0[8], acc1[8];
    #pragma unroll
    for (int i = 0; i < 8; i++) { acc0[i] = di * selfv[i]; acc1[i] = 0.0f; }
    int e0 = row_ptr[node], e1 = row_ptr[node + 1];
    int e = e0;
    for (; e + 1 < e1; e += 2) {
        int s0 = csr_src[e], s1 = csr_src[e + 1];
        float w0 = dinv[s0], w1 = dinv[s1];
        uint4 u0 = h4[(size_t)s0 * DV + f];
        uint4 u1 = h4[(size_t)s1 * DV + f];
        float t0[8], t1[8];
        bf8_unpack(u0, t0);
        bf8_unpack(u1, t1);
        #pragma unroll
        for (int i = 0; i < 8; i++) { acc0[i] += w0 * t0[i]; acc1[i] += w1 * t1[i]; }
    }
    if (e < e1) {
        int s0 = csr_src[e];
        float w0 = dinv[s0];
        float t0[8];
        bf8_unpack(h4[(size_t)s0 * DV + f], t0);
        #pragma unroll
        for (int i = 0; i < 8; i++) acc0[i] += w0 * t0[i];
    }
    uint4 o;
    o.x = pack2(di * (acc0[0] + acc1[0]), di * (acc0[1] + acc1[1]));
    o.y = pack2(di * (acc0[2] + acc1[2]), di * (acc0[3] + acc1[3]));
    o.z = pack2(di * (acc0[4] + acc1[4]), di * (acc0[5] + acc1[5]));
    o.w = pack2(di * (acc0[6] + acc1[6]), di * (acc0[7] + acc1[7]));
    ((uint4*)out)[(size_t)node * DV + f] = o;
}

// ---------------- layer-1 matmul (K=5): bf16 out = relu(Hin @ W + b) ----------------
template<int DIN, int DOUT>
__global__ void k_matmul(const float* __restrict__ Hin, const float* __restrict__ W,
                         const float* __restrict__ bias, unsigned short* __restrict__ Hout) {
    constexpr int G = 256 / DOUT;
    constexpr int ROWS = 16;
    constexpr int RPB = G * ROWS;
    __shared__ float lds[RPB * DIN];
    int t = threadIdx.x;
    int row0 = blockIdx.x * RPB;
    const int base = row0 * DIN;
    const int lim = N_NODES * DIN - base;
    for (int idx = t; idx < RPB * DIN; idx += 256)
        lds[idx] = (idx < lim) ? Hin[base + idx] : 0.0f;
    __syncthreads();
    int j = t % DOUT;
    int g = t / DOUT;
    float b = bias[j];
    float acc[ROWS];
    #pragma unroll
    for (int r = 0; r < ROWS; r++) acc[r] = 0.0f;
    for (int k = 0; k < DIN; k++) {
        float w = W[k * DOUT + j];
        #pragma unroll
        for (int r = 0; r < ROWS; r++)
            acc[r] += lds[(g * ROWS + r) * DIN + k] * w;
    }
    #pragma unroll
    for (int r = 0; r < ROWS; r++) {
        int gr = row0 + g * ROWS + r;
        if (gr < N_NODES) {
            float v = acc[r] + b;
            Hout[gr * DOUT + j] = f2bf(v > 0.0f ? v : 0.0f);
        }
    }
}

// ---------------- pack W (fp32, row-major KxN) into MFMA B-fragment layout ----------------
template<int K, int N>
__global__ void k_packW(const float* __restrict__ W, unsigned short* __restrict__ Wp) {
    constexpr int KT = K / 32;
    int bid = blockIdx.x;            // nt*KT + kt
    int kt = bid % KT, nt = bid / KT;
    int l = threadIdx.x;             // 0..63
    int m = l & 15, quad = l >> 4;
    #pragma unroll
    for (int j = 0; j < 8; j++) {
        int k = kt * 32 + quad * 8 + j;
        int n = nt * 16 + m;
        Wp[((size_t)bid * 64 + l) * 8 + j] = f2bf(W[(size_t)k * N + n]);
    }
}

// ---------------- MFMA GEMM: C = relu(A @ W + b), A bf16 [M x K], Wp packed bf16 ----------------
template<int K, int N, bool OBF>
__global__ __launch_bounds__(256) void k_gemm_mfma(const unsigned short* __restrict__ A,
                                                   const unsigned short* __restrict__ Wp,
                                                   const float* __restrict__ bias,
                                                   void* __restrict__ Cv) {
    constexpr int KT = K / 32, NT = N / 16;
    int wave = threadIdx.x >> 6, lane = threadIdx.x & 63;
    int wid = blockIdx.x * 4 + wave;
    int mt0 = wid * 2;
    if (mt0 >= MTILES) return;
    bool two = (mt0 + 1) < MTILES;
    int m = lane & 15, quad = lane >> 4;
    bf16x8 a0[KT], a1[KT];
    #pragma unroll
    for (int kt = 0; kt < KT; kt++) {
        a0[kt] = *(const bf16x8*)(A + (size_t)(mt0 * 16 + m) * K + kt * 32 + quad * 8);
        a1[kt] = *(const bf16x8*)(A + (size_t)((mt0 + 1) * 16 + m) * K + kt * 32 + quad * 8);
    }
    const bf16x8* Bp = (const bf16x8*)Wp;
    for (int nt = 0; nt < NT; nt++) {
        f32x4 c0 = {0.f, 0.f, 0.f, 0.f}, c1 = {0.f, 0.f, 0.f, 0.f};
        #pragma unroll
        for (int kt = 0; kt < KT; kt++) {
            bf16x8 b = Bp[(size_t)(nt * KT + kt) * 64 + lane];
            c0 = __builtin_amdgcn_mfma_f32_16x16x32_bf16(a0[kt], b, c0, 0, 0, 0);
            c1 = __builtin_amdgcn_mfma_f32_16x16x32_bf16(a1[kt], b, c1, 0, 0, 0);
        }
        int col = nt * 16 + m;
        float bv = bias[col];
        #pragma unroll
        for (int r = 0; r < 4; r++) {
            int row0 = mt0 * 16 + quad * 4 + r;
            float v0 = fmaxf(c0[r] + bv, 0.f);
            if constexpr (OBF) ((unsigned short*)Cv)[(size_t)row0 * N + col] = f2bf(v0);
            else               ((float*)Cv)[(size_t)row0 * N + col] = v0;
            if (two) {
                int row1 = row0 + 16;
                float v1 = fmaxf(c1[r] + bv, 0.f);
                if constexpr (OBF) ((unsigned short*)Cv)[(size_t)row1 * N + col] = f2bf(v1);
                else               ((float*)Cv)[(size_t)row1 * N + col] = v1;
            }
        }
    }
}

// ---------------- graph counts via binary search (batch is sorted) ----------------
__global__ void k_counts_bs(const int* __restrict__ batch, float* gcount) {
    int g = threadIdx.x;
    if (g >= N_GRAPHS) return;
    int lo = 0, hi = N_NODES;
    while (lo < hi) { int m = (lo + hi) >> 1; if (batch[m] < g) lo = m + 1; else hi = m; }
    int start = lo;
    lo = 0; hi = N_NODES;
    while (lo < hi) { int m = (lo + hi) >> 1; if (batch[m] < g + 1) lo = m + 1; else hi = m; }
    gcount[g] = (float)(lo - start);
}

// ---------------- pooling (bf16 h) ----------------
#define POOL_CHUNK 64
__global__ void k_poolb(const unsigned short* __restrict__ h, const int* __restrict__ batch,
                        float* pooled) {
    int t = threadIdx.x;                 // feature 0..255
    int n0 = blockIdx.x * POOL_CHUNK;
    int n1 = n0 + POOL_CHUNK; if (n1 > N_NODES) n1 = N_NODES;
    float acc = 0.0f;
    int cur = batch[n0];
    for (int i = n0; i < n1; i++) {
        int g = batch[i];
        if (g != cur) {
            atomicAdd(&pooled[cur * 256 + t], acc);
            acc = 0.0f; cur = g;
        }
        acc += bf2f(h[(size_t)i * 256 + t]);
    }
    atomicAdd(&pooled[cur * 256 + t], acc);
}

// ---------------- FC + log_softmax (one wave per graph) ----------------
__global__ void k_final(const float* __restrict__ pooled, const float* __restrict__ gcount,
                        const float* __restrict__ fcW, const float* __restrict__ fcb,
                        float* __restrict__ out) {
    int g = blockIdx.x;
    int t = threadIdx.x;                 // 0..63
    float p[4];
    #pragma unroll
    for (int m = 0; m < 4; m++) p[m] = pooled[g * 256 + t + 64 * m];
    float inv = 1.0f / fmaxf(gcount[g], 1.0f);
    float logits[NUM_CLASSES];
    #pragma unroll
    for (int j = 0; j < NUM_CLASSES; j++) {
        float s = 0.0f;
        #pragma unroll
        for (int m = 0; m < 4; m++) s += p[m] * fcW[(t + 64 * m) * NUM_CLASSES + j];
        for (int off = 32; off > 0; off >>= 1) s += __shfl_xor(s, off);
        logits[j] = s * inv + fcb[j];
    }
    float mx = logits[0];
    #pragma unroll
    for (int j = 1; j < NUM_CLASSES; j++) mx = fmaxf(mx, logits[j]);
    float se = 0.0f;
    #pragma unroll
    for (int j = 0; j < NUM_CLASSES; j++) se += expf(logits[j] - mx);
    float lse = mx + logf(se);
    if (t < NUM_CLASSES) out[g * NUM_CLASSES + t] = logits[t] - lse;
}

extern "C" void kernel_launch(void* const* d_in, const int* in_sizes, int n_in,
                              void* d_out, int out_size, void* d_ws, size_t ws_size,
                              hipStream_t stream) {
    const float* x     = (const float*)d_in[0];
    const int*   ei    = (const int*)d_in[1];
    const int*   src   = ei;
    const int*   dst   = ei + N_EDGES;
    const int*   batch = (const int*)d_in[2];
    const float* W1 = (const float*)d_in[3];  const float* b1 = (const float*)d_in[4];
    const float* W2 = (const float*)d_in[5];  const float* b2 = (const float*)d_in[6];
    const float* W3 = (const float*)d_in[7];  const float* b3 = (const float*)d_in[8];
    const float* W4 = (const float*)d_in[9];  const float* b4 = (const float*)d_in[10];
    const float* fcW = (const float*)d_in[11]; const float* fcb = (const float*)d_in[12];
    float* out = (float*)d_out;

    char* ws = (char*)d_ws;
    float* bufA     = (float*)ws; ws += (size_t)N_NODES * 256 * 4;   // agg out
    float* bufB     = (float*)ws; ws += (size_t)N_NODES * 256 * 4;   // h (bf16)
    float* dinv     = (float*)ws; ws += (size_t)N_NODES * 4;
    int*   row_ptr  = (int*)ws;   ws += (size_t)(N_NODES + 4) * 4;
    int*   csr_src  = (int*)ws;   ws += (size_t)N_EDGES * 4;
    unsigned int* binned = (unsigned int*)ws; ws += (size_t)N_EDGES * 4;
    int*   bin_cnt  = (int*)ws;   ws += (NBINS + 4) * 4;
    int*   bin_start= (int*)ws;   ws += (NBINS + 4) * 4;
    int*   bin_cur  = (int*)ws;   ws += (NBINS + 4) * 4;
    float* pooled   = (float*)ws; ws += (size_t)N_GRAPHS * 256 * 4;
    float* gcount   = (float*)ws; ws += (size_t)N_GRAPHS * 4;
    unsigned short* wp2 = (unsigned short*)ws; ws += 32 * 64 * 2;
    unsigned short* wp3 = (unsigned short*)ws; ws += 64 * 128 * 2;
    unsigned short* wp4 = (unsigned short*)ws; ws += 128 * 256 * 2;
    unsigned short* hb = (unsigned short*)bufB;   // bf16 h
    unsigned short* ab = (unsigned short*)bufA;   // bf16 agg out

    const int TB = 256;
    // init + weight packing + binned CSR build
    k_init<<<(N_GRAPHS * 256 + TB - 1) / TB, TB, 0, stream>>>(pooled, bin_cnt);
    k_packW<32, 64><<<1 * 4, 64, 0, stream>>>(W2, wp2);
    k_packW<64, 128><<<2 * 8, 64, 0, stream>>>(W3, wp3);
    k_packW<128, 256><<<4 * 16, 64, 0, stream>>>(W4, wp4);
    k_hist<<<NCHUNKS, TB, 0, stream>>>(dst, bin_cnt);
    k_binscan<<<1, TB, 0, stream>>>(bin_cnt, bin_start, bin_cur);
    k_binscatter<<<NCHUNKS, TB, 0, stream>>>(src, dst, bin_cur, binned);
    k_csr<<<NBINS, TB, 0, stream>>>(binned, bin_start, row_ptr, dinv, csr_src);
    k_counts_bs<<<1, 64, 0, stream>>>(batch, gcount);

    const int GEMM_BLOCKS = ((MTILES + 1) / 2 + 3) / 4;   // 391
    // layer 1: agg(x)[5] -> mm 5->32 (bf16 out)
    k_agg5<<<(N_NODES + 31) / 32, TB, 0, stream>>>(x, row_ptr, csr_src, dinv, bufA);
    k_matmul<5, 32><<<(N_NODES + 127) / 128, TB, 0, stream>>>(bufA, W1, b1, hb);
    // layer 2: agg[32] -> mfma gemm 32->64
    k_aggb<32><<<(N_NODES + 63) / 64, TB, 0, stream>>>(hb, row_ptr, csr_src, dinv, ab);
    k_gemm_mfma<32, 64, true><<<GEMM_BLOCKS, TB, 0, stream>>>(ab, wp2, b2, hb);
    // layer 3: agg[64] -> mfma gemm 64->128
    k_aggb<64><<<(N_NODES + 31) / 32, TB, 0, stream>>>(hb, row_ptr, csr_src, dinv, ab);
    k_gemm_mfma<64, 128, true><<<GEMM_BLOCKS, TB, 0, stream>>>(ab, wp3, b3, hb);
    // layer 4: agg[128] -> mfma gemm 128->256 (bf16 out)
    k_aggb<128><<<(N_NODES + 15) / 16, TB, 0, stream>>>(hb, row_ptr, csr_src, dinv, ab);
    k_gemm_mfma<128, 256, true><<<GEMM_BLOCKS, TB, 0, stream>>>(ab, wp4, b4, hb);

    // pooling + classifier
    k_poolb<<<(N_NODES + POOL_CHUNK - 1) / POOL_CHUNK, TB, 0, stream>>>(hb, batch, pooled);
    k_final<<<N_GRAPHS, 64, 0, stream>>>(pooled, gcount, fcW, fcb, out);
}